// Round 3
// baseline (1675.702 us; speedup 1.0000x reference)
//
#include <hip/hip_runtime.h>

#define N_NODES 200000
#define N_EDGES 6400000
#define EMB 16
#define CONT 12
#define H 128
#define IN_DIM 60   // 3*EMB + CONT
#define NPB 32      // nodes per block for dense kernels
#define TPB 256

#define BROWS 128                                    // rows per bucket
#define NBUCK ((N_NODES + BROWS - 1) / BROWS)        // 1563
#define SORT_TILE 16384
#define SORT_TPB 512
#define N_SORT_BLOCKS ((N_EDGES + SORT_TILE - 1) / SORT_TILE)  // 391

typedef float vfloat4 __attribute__((ext_vector_type(4)));  // true vector type
                                                            // (nontemporal ok)

// bf16 round-to-nearest-even pack helper (h >= 0, finite)
__device__ __forceinline__ unsigned bf_rne(float f) {
    unsigned u = __float_as_uint(f);
    return (u + 0x7FFFu + ((u >> 16) & 1u)) >> 16;
}

// ---------------------------------------------------------------------------
// K1: fused embedding gather + 2-layer input MLP + optional bf16 pack.
// 4x4 register blocking: FMA-bound, LDS broadcast reads. (proven r4)
// ---------------------------------------------------------------------------
__global__ __launch_bounds__(TPB) void k_input_mlp(
    const int* __restrict__ midx, const int* __restrict__ widx,
    const int* __restrict__ tidx, const float* __restrict__ cont,
    const float* __restrict__ memb, const float* __restrict__ wemb,
    const float* __restrict__ temb,
    const float* __restrict__ W1, const float* __restrict__ b1,
    const float* __restrict__ W2, const float* __restrict__ b2,
    float* __restrict__ h, unsigned* __restrict__ hb)
{
    __shared__ float x_lds[NPB][IN_DIM];
    __shared__ float h0_lds[NPB][H];
    const int tid  = threadIdx.x;
    const int base = blockIdx.x * NPB;

    for (int idx = tid; idx < NPB * IN_DIM; idx += TPB) {
        int n = idx / IN_DIM, k = idx % IN_DIM;
        int node = base + n;
        float v;
        if (k < 16)       v = memb[midx[node] * 16 + k];
        else if (k < 32)  v = wemb[widx[node] * 16 + (k - 16)];
        else if (k < 48)  v = temb[tidx[node] * 16 + (k - 32)];
        else              v = cont[(size_t)node * CONT + (k - 48)];
        x_lds[n][k] = v;
    }
    __syncthreads();

    const int c0 = (tid & 31) * 4;
    const int r0 = (tid >> 5) * 4;

    float acc[4][4];
    #pragma unroll
    for (int i = 0; i < 4; i++)
        #pragma unroll
        for (int j = 0; j < 4; j++) acc[i][j] = 0.f;

    for (int k = 0; k < IN_DIM; k += 4) {
        float4 a[4];
        #pragma unroll
        for (int i = 0; i < 4; i++) a[i] = *(const float4*)&x_lds[r0 + i][k];
        #pragma unroll
        for (int kk = 0; kk < 4; kk++) {
            float4 w = *(const float4*)(W1 + (size_t)(k + kk) * H + c0);
            const float* wf = (const float*)&w;
            #pragma unroll
            for (int i = 0; i < 4; i++) {
                float av = ((const float*)&a[i])[kk];
                #pragma unroll
                for (int j = 0; j < 4; j++)
                    acc[i][j] += av * wf[j];
            }
        }
    }
    {
        float4 bv = *(const float4*)(b1 + c0);
        const float* bf = (const float*)&bv;
        #pragma unroll
        for (int i = 0; i < 4; i++)
            #pragma unroll
            for (int j = 0; j < 4; j++)
                h0_lds[r0 + i][c0 + j] = fmaxf(acc[i][j] + bf[j], 0.f);
    }
    __syncthreads();

    #pragma unroll
    for (int i = 0; i < 4; i++)
        #pragma unroll
        for (int j = 0; j < 4; j++) acc[i][j] = 0.f;

    for (int k = 0; k < H; k += 4) {
        float4 a[4];
        #pragma unroll
        for (int i = 0; i < 4; i++) a[i] = *(const float4*)&h0_lds[r0 + i][k];
        #pragma unroll
        for (int kk = 0; kk < 4; kk++) {
            float4 w = *(const float4*)(W2 + (size_t)(k + kk) * H + c0);
            const float* wf = (const float*)&w;
            #pragma unroll
            for (int i = 0; i < 4; i++) {
                float av = ((const float*)&a[i])[kk];
                #pragma unroll
                for (int j = 0; j < 4; j++)
                    acc[i][j] += av * wf[j];
            }
        }
    }
    {
        float4 bv = *(const float4*)(b2 + c0);
        const float* bf = (const float*)&bv;
        #pragma unroll
        for (int i = 0; i < 4; i++) {
            int node = base + r0 + i;
            float4 out;
            float* of = (float*)&out;
            #pragma unroll
            for (int j = 0; j < 4; j++)
                of[j] = fmaxf(acc[i][j] + bf[j], 0.f);
            *(float4*)(h + (size_t)node * H + c0) = out;
            if (hb) {
                uint2 p;
                p.x = bf_rne(of[0]) | (bf_rne(of[1]) << 16);
                p.y = bf_rne(of[2]) | (bf_rne(of[3]) << 16);
                *(uint2*)(hb + (size_t)node * 64 + (c0 >> 1)) = p;
            }
        }
    }
}

// ---------------------------------------------------------------------------
// CSR build, two-phase write-combined:
//   hist -> scan -> phase1 bucket scatter (tile-segmented) -> phase2 row sort
// Entry format: low24 = col, bits24..31 = row-within-bucket, high32 = val.
// ---------------------------------------------------------------------------
__global__ __launch_bounds__(256) void k_bucket_hist(
    const int* __restrict__ erow, int* __restrict__ bhist)
{
    __shared__ int lh[NBUCK];
    for (int i = threadIdx.x; i < NBUCK; i += 256) lh[i] = 0;
    __syncthreads();
    for (int e = blockIdx.x * 256 + threadIdx.x; e < N_EDGES; e += gridDim.x * 256)
        atomicAdd(&lh[erow[e] >> 7], 1);
    __syncthreads();
    for (int i = threadIdx.x; i < NBUCK; i += 256) {
        int v = lh[i];
        if (v) atomicAdd(&bhist[i], v);
    }
}

__global__ __launch_bounds__(1024) void k_scan_buckets(
    const int* __restrict__ bhist, int* __restrict__ bucket_off,
    int* __restrict__ bucket_cur, int* __restrict__ row_ptr)
{
    __shared__ int s[1024];
    int t = threadIdx.x;
    int i0 = t * 2, i1 = t * 2 + 1;
    int v0 = (i0 < NBUCK) ? bhist[i0] : 0;
    int v1 = (i1 < NBUCK) ? bhist[i1] : 0;
    s[t] = v0 + v1;
    __syncthreads();
    for (int off = 1; off < 1024; off <<= 1) {
        int u = (t >= off) ? s[t - off] : 0;
        __syncthreads();
        s[t] += u;
        __syncthreads();
    }
    int base = (t > 0) ? s[t - 1] : 0;
    if (i0 < NBUCK) { bucket_off[i0] = base;      bucket_cur[i0] = base; }
    if (i1 < NBUCK) { bucket_off[i1] = base + v0; bucket_cur[i1] = base + v0; }
    if (t == 1023) {
        bucket_off[NBUCK] = s[1023];      // == N_EDGES
        row_ptr[N_NODES]  = s[1023];
    }
}

// phase 1: scatter to bucket granularity. Each tile reserves contiguous
// per-bucket segments so a segment's writes come from one block (one XCD):
// L2 write-combines lines (r5 evidence: exact-row scatter had 7.7x write amp).
__global__ __launch_bounds__(SORT_TPB) void k_bucket_sort(
    const int* __restrict__ erow, const int* __restrict__ ecol,
    const float* __restrict__ eval, int* __restrict__ bucket_cur,
    long long* __restrict__ bkt)
{
    __shared__ int hist[NBUCK];
    __shared__ int gbase[NBUCK];
    __shared__ int fcur[NBUCK];
    const int t = threadIdx.x;
    const int tile0 = blockIdx.x * SORT_TILE;
    const int nE = min(SORT_TILE, N_EDGES - tile0);

    for (int i = t; i < NBUCK; i += SORT_TPB) { hist[i] = 0; fcur[i] = 0; }
    __syncthreads();
    for (int i = t; i < nE; i += SORT_TPB)
        atomicAdd(&hist[erow[tile0 + i] >> 7], 1);
    __syncthreads();
    for (int i = t; i < NBUCK; i += SORT_TPB) {
        int c = hist[i];
        if (c) gbase[i] = atomicAdd(&bucket_cur[i], c);
    }
    __syncthreads();
    for (int i = t; i < nE; i += SORT_TPB) {
        int r = erow[tile0 + i];
        int b = r >> 7;
        int off = atomicAdd(&fcur[b], 1);
        unsigned w0 = (unsigned)ecol[tile0 + i] | ((unsigned)(r & 127) << 24);
        unsigned w1 = (unsigned)__float_as_int(eval[tile0 + i]);
        bkt[gbase[b] + off] = (long long)(((unsigned long long)w1 << 32) | w0);
    }
}

// phase 2: one block per bucket. Count rows -> scan -> scatter to exact-row
// CSR order within the bucket's own window (single-block L2 locality).
__global__ __launch_bounds__(512) void k_row_sort(
    const int* __restrict__ bucket_off, const long long* __restrict__ bkt,
    long long* __restrict__ csr, int* __restrict__ row_ptr)
{
    __shared__ int cnt[BROWS];
    __shared__ int cur[BROWS];
    const int t = threadIdx.x;
    const int b = blockIdx.x;
    const int start = bucket_off[b];
    const int end   = bucket_off[b + 1];
    const int n = end - start;

    if (t < BROWS) cnt[t] = 0;
    __syncthreads();
    for (int i = t; i < n; i += 512) {
        int w0 = ((const int2*)bkt)[start + i].x;
        atomicAdd(&cnt[(unsigned)w0 >> 24], 1);
    }
    __syncthreads();
    if (t < BROWS) cur[t] = cnt[t];
    __syncthreads();
    for (int off = 1; off < BROWS; off <<= 1) {
        int v = 0;
        if (t < BROWS && t >= off) v = cur[t - off];
        __syncthreads();
        if (t < BROWS) cur[t] += v;
        __syncthreads();
    }
    if (t < BROWS) {
        int excl = cur[t] - cnt[t];          // exclusive scan
        cur[t] = excl;                       // becomes cursor
        int row = b * BROWS + t;
        if (row < N_NODES) row_ptr[row] = start + excl;
    }
    __syncthreads();
    for (int i = t; i < n; i += 512) {
        long long ed = bkt[start + i];
        int lr = (int)((unsigned)ed >> 24);
        int p = atomicAdd(&cur[lr], 1);
        csr[start + p] = ed;
    }
}

// ---------------------------------------------------------------------------
// K2: CSR SpMM — one wave per row, register accumulation, bf16 gathers,
// 8 edges in flight per wave. CSR stream + neigh output are single-use:
// nontemporal so they don't evict the hot 51.2 MB hb gather table from L2.
// ---------------------------------------------------------------------------
__global__ __launch_bounds__(TPB) void k_spmm_csr_bf16(
    const int* __restrict__ row_ptr, const long long* __restrict__ csr,
    const unsigned* __restrict__ hb, float* __restrict__ neigh)
{
    int row = (int)((blockIdx.x * TPB + threadIdx.x) >> 6);
    if (row >= N_NODES) return;
    int lane = threadIdx.x & 63;

    int e   = row_ptr[row];
    int end = row_ptr[row + 1];

    float ax = 0.f, ay = 0.f;
    for (; e + 8 <= end; e += 8) {
        long long cd[8];
        #pragma unroll
        for (int k = 0; k < 8; k++) cd[k] = __builtin_nontemporal_load(csr + e + k);
        unsigned gv[8];
        #pragma unroll
        for (int k = 0; k < 8; k++)
            gv[k] = hb[(size_t)((unsigned)cd[k] & 0xFFFFFFu) * 64 + lane];
        #pragma unroll
        for (int k = 0; k < 8; k++) {
            float v = __int_as_float((int)((unsigned long long)cd[k] >> 32));
            ax += v * __uint_as_float(gv[k] << 16);
            ay += v * __uint_as_float(gv[k] & 0xFFFF0000u);
        }
    }
    for (; e < end; e++) {
        long long cd = __builtin_nontemporal_load(csr + e);
        unsigned g = hb[(size_t)((unsigned)cd & 0xFFFFFFu) * 64 + lane];
        float v = __int_as_float((int)((unsigned long long)cd >> 32));
        ax += v * __uint_as_float(g << 16);
        ay += v * __uint_as_float(g & 0xFFFF0000u);
    }
    float* dst = neigh + (size_t)row * H + lane * 2;
    __builtin_nontemporal_store(ax, dst);
    __builtin_nontemporal_store(ay, dst + 1);
}

// f32-gather variant (tier B: no hb buffer)
__global__ __launch_bounds__(TPB) void k_spmm_csr_f32(
    const int* __restrict__ row_ptr, const long long* __restrict__ csr,
    const float* __restrict__ h, float* __restrict__ neigh)
{
    int row = (int)((blockIdx.x * TPB + threadIdx.x) >> 6);
    if (row >= N_NODES) return;
    int lane = threadIdx.x & 63;
    int e   = row_ptr[row];
    int end = row_ptr[row + 1];
    float ax = 0.f, ay = 0.f;
    for (; e + 4 <= end; e += 4) {
        long long cd[4];
        #pragma unroll
        for (int k = 0; k < 4; k++) cd[k] = __builtin_nontemporal_load(csr + e + k);
        float2 gv[4];
        #pragma unroll
        for (int k = 0; k < 4; k++)
            gv[k] = *((const float2*)(h + (size_t)((unsigned)cd[k] & 0xFFFFFFu) * H) + lane);
        #pragma unroll
        for (int k = 0; k < 4; k++) {
            float v = __int_as_float((int)((unsigned long long)cd[k] >> 32));
            ax += v * gv[k].x;
            ay += v * gv[k].y;
        }
    }
    for (; e < end; e++) {
        long long cd = __builtin_nontemporal_load(csr + e);
        float2 gv = *((const float2*)(h + (size_t)((unsigned)cd & 0xFFFFFFu) * H) + lane);
        float v = __int_as_float((int)((unsigned long long)cd >> 32));
        ax += v * gv.x;
        ay += v * gv.y;
    }
    float* dst = neigh + (size_t)row * H + lane * 2;
    __builtin_nontemporal_store(ax, dst);
    __builtin_nontemporal_store(ay, dst + 1);
}

// Tier C fallback: atomic SpMM
__global__ __launch_bounds__(TPB) void k_spmm_atomic(
    const int* __restrict__ erow, const int* __restrict__ ecol,
    const float* __restrict__ eval, const float* __restrict__ h,
    float* __restrict__ neigh)
{
    unsigned int gid = blockIdx.x * TPB + threadIdx.x;
    int e = (int)(gid >> 5);
    if (e >= N_EDGES) return;
    int c = ((int)gid & 31) * 4;
    int col = ecol[e];
    int row = erow[e];
    float v = eval[e];
    const float4 hv = *(const float4*)(h + (size_t)col * H + c);
    float* dst = neigh + (size_t)row * H + c;
    unsafeAtomicAdd(dst + 0, v * hv.x);
    unsafeAtomicAdd(dst + 1, v * hv.y);
    unsafeAtomicAdd(dst + 2, v * hv.z);
    unsafeAtomicAdd(dst + 3, v * hv.w);
}

// ---------------------------------------------------------------------------
// K3: dense layer update: h += relu(h@Ws + bs + neigh@Wn + bn)  (in place)
// 4x4 register blocking + optional fused bf16 pack + (l==1) fused mean/max
// pooling epilogue. neigh read is single-use -> nontemporal (keep L2 for hb).
// ---------------------------------------------------------------------------
__global__ __launch_bounds__(TPB) void k_layer_dense(
    const float* __restrict__ neigh,
    const float* __restrict__ Wself, const float* __restrict__ bself,
    const float* __restrict__ Wneigh, const float* __restrict__ bneigh,
    float* __restrict__ h, unsigned* __restrict__ hb,
    float* __restrict__ gout, int do_pool)
{
    __shared__ float h_lds[NPB][H];
    __shared__ float n_lds[NPB][H];
    __shared__ float psum[8][H];
    __shared__ float pmax[8][H];
    const int tid  = threadIdx.x;
    const int base = blockIdx.x * NPB;

    for (int idx = tid; idx < NPB * H / 4; idx += TPB) {
        int r = idx >> 5, c = (idx & 31) * 4;
        *(float4*)&h_lds[r][c] = *(const float4*)(h + (size_t)(base + r) * H + c);
        vfloat4 nv = __builtin_nontemporal_load(
            (const vfloat4*)(neigh + (size_t)(base + r) * H + c));
        *(vfloat4*)&n_lds[r][c] = nv;
    }
    __syncthreads();

    const int c0 = (tid & 31) * 4;
    const int r0 = (tid >> 5) * 4;
    const int grp = tid >> 5;

    float acc[4][4];
    #pragma unroll
    for (int i = 0; i < 4; i++)
        #pragma unroll
        for (int j = 0; j < 4; j++) acc[i][j] = 0.f;

    for (int k = 0; k < H; k += 4) {
        float4 a[4], b[4];
        #pragma unroll
        for (int i = 0; i < 4; i++) {
            a[i] = *(const float4*)&h_lds[r0 + i][k];
            b[i] = *(const float4*)&n_lds[r0 + i][k];
        }
        #pragma unroll
        for (int kk = 0; kk < 4; kk++) {
            float4 ws = *(const float4*)(Wself  + (size_t)(k + kk) * H + c0);
            float4 wn = *(const float4*)(Wneigh + (size_t)(k + kk) * H + c0);
            const float* wsf = (const float*)&ws;
            const float* wnf = (const float*)&wn;
            #pragma unroll
            for (int i = 0; i < 4; i++) {
                float av = ((const float*)&a[i])[kk];
                float bv = ((const float*)&b[i])[kk];
                #pragma unroll
                for (int j = 0; j < 4; j++)
                    acc[i][j] += av * wsf[j] + bv * wnf[j];
            }
        }
    }

    float4 bs = *(const float4*)(bself + c0);
    float4 bn = *(const float4*)(bneigh + c0);
    const float* bsf = (const float*)&bs;
    const float* bnf = (const float*)&bn;
    float csum[4] = {0.f, 0.f, 0.f, 0.f};
    float cmax[4] = {0.f, 0.f, 0.f, 0.f};
    #pragma unroll
    for (int i = 0; i < 4; i++) {
        int node = base + r0 + i;
        float4 out;
        float* of = (float*)&out;
        #pragma unroll
        for (int j = 0; j < 4; j++) {
            float v = fmaxf(acc[i][j] + bsf[j] + bnf[j], 0.f);
            of[j] = h_lds[r0 + i][c0 + j] + v;
            csum[j] += of[j];
            cmax[j] = fmaxf(cmax[j], of[j]);
        }
        *(float4*)(h + (size_t)node * H + c0) = out;
        if (hb) {
            uint2 p;
            p.x = bf_rne(of[0]) | (bf_rne(of[1]) << 16);
            p.y = bf_rne(of[2]) | (bf_rne(of[3]) << 16);
            *(uint2*)(hb + (size_t)node * 64 + (c0 >> 1)) = p;
        }
    }

    if (do_pool) {
        #pragma unroll
        for (int j = 0; j < 4; j++) {
            psum[grp][c0 + j] = csum[j];
            pmax[grp][c0 + j] = cmax[j];
        }
        __syncthreads();
        if (tid < H) {
            float s = 0.f, m = 0.f;
            #pragma unroll
            for (int gix = 0; gix < 8; gix++) {
                s += psum[gix][tid];
                m = fmaxf(m, pmax[gix][tid]);
            }
            unsafeAtomicAdd(&gout[tid], s);
            atomicMax((int*)&gout[H + tid], __float_as_int(m));
        }
    }
}

__global__ void k_finalize(float* __restrict__ g)
{
    int t = threadIdx.x;
    if (t < 128) g[t] *= (1.0f / (float)N_NODES);
}

// ---------------------------------------------------------------------------
extern "C" void kernel_launch(void* const* d_in, const int* in_sizes, int n_in,
                              void* d_out, int out_size, void* d_ws, size_t ws_size,
                              hipStream_t stream)
{
    const int*   midx  = (const int*)  d_in[0];
    const int*   widx  = (const int*)  d_in[1];
    const int*   tidx  = (const int*)  d_in[2];
    const float* cont  = (const float*)d_in[3];
    const int*   erow  = (const int*)  d_in[4];
    const int*   ecol  = (const int*)  d_in[5];
    const float* eval  = (const float*)d_in[6];
    const float* memb  = (const float*)d_in[7];
    const float* wemb  = (const float*)d_in[8];
    const float* temb  = (const float*)d_in[9];
    const float* W1    = (const float*)d_in[10];
    const float* b1    = (const float*)d_in[11];
    const float* W2    = (const float*)d_in[12];
    const float* b2    = (const float*)d_in[13];
    const float* Wself = (const float*)d_in[14];
    const float* bself = (const float*)d_in[15];
    const float* Wneigh= (const float*)d_in[16];
    const float* bneigh= (const float*)d_in[17];

    float* g = (float*)d_out;   // [256]
    float* h = g + 256;         // [N, H] lives in d_out

    // ---- workspace layout ----
    // neigh: 102.4 MB.  bkt (phase-1 buffer, 51.2 MB) ALIASES neigh: it is
    // fully consumed by k_row_sort before the first SpMM writes neigh.
    const size_t neigh_elems = (size_t)N_NODES * H;      // 25.6 M floats
    const size_t hb_elems    = (size_t)N_NODES * H / 2;  // 12.8 M u32

    float*     neigh = (float*)d_ws;
    long long* bkt   = (long long*)d_ws;                 // alias (see above)

    // tier A layout (with hb)
    unsigned*  hb    = (unsigned*)(neigh + neigh_elems);
    long long* csrA  = (long long*)(hb + hb_elems);
    // tier B layout (no hb)
    long long* csrB  = (long long*)(neigh + neigh_elems);

    const size_t tail_ints   = (size_t)(N_NODES + 2) + NBUCK + (NBUCK + 1) + NBUCK + 16;
    const size_t tierB_bytes = neigh_elems * 4 + (size_t)N_EDGES * 8 + tail_ints * 4;
    const size_t tierA_bytes = tierB_bytes + hb_elems * 4;
    const bool tierA = (ws_size >= tierA_bytes);
    const bool tierB = (ws_size >= tierB_bytes);

    long long* csr = tierA ? csrA : csrB;
    int* row_ptr    = (int*)(csr + N_EDGES);   // N+2
    int* bhist      = row_ptr + N_NODES + 2;   // NBUCK
    int* bucket_off = bhist + NBUCK;           // NBUCK+1
    int* bucket_cur = bucket_off + NBUCK + 1;  // NBUCK

    hipMemsetAsync(d_out, 0, 256 * sizeof(float), stream);

    k_input_mlp<<<N_NODES / NPB, TPB, 0, stream>>>(
        midx, widx, tidx, cont, memb, wemb, temb, W1, b1, W2, b2, h,
        tierA ? hb : nullptr);

    if (tierB) {
        hipMemsetAsync(bhist, 0, NBUCK * sizeof(int), stream);
        k_bucket_hist<<<2048, 256, 0, stream>>>(erow, bhist);
        k_scan_buckets<<<1, 1024, 0, stream>>>(bhist, bucket_off, bucket_cur, row_ptr);
        k_bucket_sort<<<N_SORT_BLOCKS, SORT_TPB, 0, stream>>>(
            erow, ecol, eval, bucket_cur, bkt);
        k_row_sort<<<NBUCK, 512, 0, stream>>>(bucket_off, bkt, csr, row_ptr);

        for (int l = 0; l < 2; l++) {
            if (tierA) {
                k_spmm_csr_bf16<<<(N_NODES * 64 + TPB - 1) / TPB, TPB, 0, stream>>>(
                    row_ptr, csr, hb, neigh);
            } else {
                k_spmm_csr_f32<<<(N_NODES * 64 + TPB - 1) / TPB, TPB, 0, stream>>>(
                    row_ptr, csr, h, neigh);
            }
            k_layer_dense<<<N_NODES / NPB, TPB, 0, stream>>>(
                neigh, Wself + (size_t)l * H * H, bself + (size_t)l * H,
                Wneigh + (size_t)l * H * H, bneigh + (size_t)l * H, h,
                (tierA && l == 0) ? hb : nullptr, g, (l == 1) ? 1 : 0);
        }
    } else {
        for (int l = 0; l < 2; l++) {
            hipMemsetAsync(neigh, 0, neigh_elems * sizeof(float), stream);
            unsigned int nthreads = (unsigned int)N_EDGES * 32u;
            k_spmm_atomic<<<nthreads / TPB, TPB, 0, stream>>>(erow, ecol, eval, h, neigh);
            k_layer_dense<<<N_NODES / NPB, TPB, 0, stream>>>(
                neigh, Wself + (size_t)l * H * H, bself + (size_t)l * H,
                Wneigh + (size_t)l * H * H, bneigh + (size_t)l * H, h,
                nullptr, g, (l == 1) ? 1 : 0);
        }
    }

    k_finalize<<<1, 128, 0, stream>>>(g);
}

// Round 4
// 1405.569 us; speedup vs baseline: 1.1922x; 1.1922x over previous
//
#include <hip/hip_runtime.h>

#define N_NODES 200000
#define N_EDGES 6400000
#define EMB 16
#define CONT 12
#define H 128
#define IN_DIM 60   // 3*EMB + CONT
#define NPB 32      // nodes per block for fallback dense kernel
#define TPB 256

#define BROWS 128                                    // rows per bucket
#define NBUCK ((N_NODES + BROWS - 1) / BROWS)        // 1563
#define SORT_TILE 16384
#define SORT_TPB 512
#define N_SORT_BLOCKS ((N_EDGES + SORT_TILE - 1) / SORT_TILE)  // 391

#define DBM 64      // nodes per block for the MFMA dense kernel

typedef __attribute__((ext_vector_type(8))) short  bf16x8;
typedef __attribute__((ext_vector_type(4))) float  f32x4;

// bf16 round-to-nearest-even pack helper (works for any finite f)
__device__ __forceinline__ unsigned bf_rne(float f) {
    unsigned u = __float_as_uint(f);
    return (u + 0x7FFFu + ((u >> 16) & 1u)) >> 16;
}

// ---------------------------------------------------------------------------
// K1: fused embedding gather + 2-layer input MLP + optional bf16 pack.
// 4x4 register blocking: FMA-bound, LDS broadcast reads. (proven r4)
// ---------------------------------------------------------------------------
__global__ __launch_bounds__(TPB) void k_input_mlp(
    const int* __restrict__ midx, const int* __restrict__ widx,
    const int* __restrict__ tidx, const float* __restrict__ cont,
    const float* __restrict__ memb, const float* __restrict__ wemb,
    const float* __restrict__ temb,
    const float* __restrict__ W1, const float* __restrict__ b1,
    const float* __restrict__ W2, const float* __restrict__ b2,
    float* __restrict__ h, unsigned* __restrict__ hb)
{
    __shared__ float x_lds[NPB][IN_DIM];
    __shared__ float h0_lds[NPB][H];
    const int tid  = threadIdx.x;
    const int base = blockIdx.x * NPB;

    for (int idx = tid; idx < NPB * IN_DIM; idx += TPB) {
        int n = idx / IN_DIM, k = idx % IN_DIM;
        int node = base + n;
        float v;
        if (k < 16)       v = memb[midx[node] * 16 + k];
        else if (k < 32)  v = wemb[widx[node] * 16 + (k - 16)];
        else if (k < 48)  v = temb[tidx[node] * 16 + (k - 32)];
        else              v = cont[(size_t)node * CONT + (k - 48)];
        x_lds[n][k] = v;
    }
    __syncthreads();

    const int c0 = (tid & 31) * 4;
    const int r0 = (tid >> 5) * 4;

    float acc[4][4];
    #pragma unroll
    for (int i = 0; i < 4; i++)
        #pragma unroll
        for (int j = 0; j < 4; j++) acc[i][j] = 0.f;

    for (int k = 0; k < IN_DIM; k += 4) {
        float4 a[4];
        #pragma unroll
        for (int i = 0; i < 4; i++) a[i] = *(const float4*)&x_lds[r0 + i][k];
        #pragma unroll
        for (int kk = 0; kk < 4; kk++) {
            float4 w = *(const float4*)(W1 + (size_t)(k + kk) * H + c0);
            const float* wf = (const float*)&w;
            #pragma unroll
            for (int i = 0; i < 4; i++) {
                float av = ((const float*)&a[i])[kk];
                #pragma unroll
                for (int j = 0; j < 4; j++)
                    acc[i][j] += av * wf[j];
            }
        }
    }
    {
        float4 bv = *(const float4*)(b1 + c0);
        const float* bf = (const float*)&bv;
        #pragma unroll
        for (int i = 0; i < 4; i++)
            #pragma unroll
            for (int j = 0; j < 4; j++)
                h0_lds[r0 + i][c0 + j] = fmaxf(acc[i][j] + bf[j], 0.f);
    }
    __syncthreads();

    #pragma unroll
    for (int i = 0; i < 4; i++)
        #pragma unroll
        for (int j = 0; j < 4; j++) acc[i][j] = 0.f;

    for (int k = 0; k < H; k += 4) {
        float4 a[4];
        #pragma unroll
        for (int i = 0; i < 4; i++) a[i] = *(const float4*)&h0_lds[r0 + i][k];
        #pragma unroll
        for (int kk = 0; kk < 4; kk++) {
            float4 w = *(const float4*)(W2 + (size_t)(k + kk) * H + c0);
            const float* wf = (const float*)&w;
            #pragma unroll
            for (int i = 0; i < 4; i++) {
                float av = ((const float*)&a[i])[kk];
                #pragma unroll
                for (int j = 0; j < 4; j++)
                    acc[i][j] += av * wf[j];
            }
        }
    }
    {
        float4 bv = *(const float4*)(b2 + c0);
        const float* bf = (const float*)&bv;
        #pragma unroll
        for (int i = 0; i < 4; i++) {
            int node = base + r0 + i;
            float4 out;
            float* of = (float*)&out;
            #pragma unroll
            for (int j = 0; j < 4; j++)
                of[j] = fmaxf(acc[i][j] + bf[j], 0.f);
            *(float4*)(h + (size_t)node * H + c0) = out;
            if (hb) {
                uint2 p;
                p.x = bf_rne(of[0]) | (bf_rne(of[1]) << 16);
                p.y = bf_rne(of[2]) | (bf_rne(of[3]) << 16);
                *(uint2*)(hb + (size_t)node * 64 + (c0 >> 1)) = p;
            }
        }
    }
}

// ---------------------------------------------------------------------------
// CSR build, two-phase write-combined:
//   hist -> scan -> phase1 bucket scatter (tile-segmented) -> phase2 row sort
// Entry format: low24 = col, bits24..31 = row-within-bucket, high32 = val.
// ---------------------------------------------------------------------------
__global__ __launch_bounds__(256) void k_bucket_hist(
    const int* __restrict__ erow, int* __restrict__ bhist)
{
    __shared__ int lh[NBUCK];
    for (int i = threadIdx.x; i < NBUCK; i += 256) lh[i] = 0;
    __syncthreads();
    for (int e = blockIdx.x * 256 + threadIdx.x; e < N_EDGES; e += gridDim.x * 256)
        atomicAdd(&lh[erow[e] >> 7], 1);
    __syncthreads();
    for (int i = threadIdx.x; i < NBUCK; i += 256) {
        int v = lh[i];
        if (v) atomicAdd(&bhist[i], v);
    }
}

__global__ __launch_bounds__(1024) void k_scan_buckets(
    const int* __restrict__ bhist, int* __restrict__ bucket_off,
    int* __restrict__ bucket_cur, int* __restrict__ row_ptr)
{
    __shared__ int s[1024];
    int t = threadIdx.x;
    int i0 = t * 2, i1 = t * 2 + 1;
    int v0 = (i0 < NBUCK) ? bhist[i0] : 0;
    int v1 = (i1 < NBUCK) ? bhist[i1] : 0;
    s[t] = v0 + v1;
    __syncthreads();
    for (int off = 1; off < 1024; off <<= 1) {
        int u = (t >= off) ? s[t - off] : 0;
        __syncthreads();
        s[t] += u;
        __syncthreads();
    }
    int base = (t > 0) ? s[t - 1] : 0;
    if (i0 < NBUCK) { bucket_off[i0] = base;      bucket_cur[i0] = base; }
    if (i1 < NBUCK) { bucket_off[i1] = base + v0; bucket_cur[i1] = base + v0; }
    if (t == 1023) {
        bucket_off[NBUCK] = s[1023];      // == N_EDGES
        row_ptr[N_NODES]  = s[1023];
    }
}

// phase 1: scatter to bucket granularity. Each tile reserves contiguous
// per-bucket segments so a segment's writes come from one block (one XCD):
// L2 write-combines lines (r5 evidence: exact-row scatter had 7.7x write amp).
__global__ __launch_bounds__(SORT_TPB) void k_bucket_sort(
    const int* __restrict__ erow, const int* __restrict__ ecol,
    const float* __restrict__ eval, int* __restrict__ bucket_cur,
    long long* __restrict__ bkt)
{
    __shared__ int hist[NBUCK];
    __shared__ int gbase[NBUCK];
    __shared__ int fcur[NBUCK];
    const int t = threadIdx.x;
    const int tile0 = blockIdx.x * SORT_TILE;
    const int nE = min(SORT_TILE, N_EDGES - tile0);

    for (int i = t; i < NBUCK; i += SORT_TPB) { hist[i] = 0; fcur[i] = 0; }
    __syncthreads();
    for (int i = t; i < nE; i += SORT_TPB)
        atomicAdd(&hist[erow[tile0 + i] >> 7], 1);
    __syncthreads();
    for (int i = t; i < NBUCK; i += SORT_TPB) {
        int c = hist[i];
        if (c) gbase[i] = atomicAdd(&bucket_cur[i], c);
    }
    __syncthreads();
    for (int i = t; i < nE; i += SORT_TPB) {
        int r = erow[tile0 + i];
        int b = r >> 7;
        int off = atomicAdd(&fcur[b], 1);
        unsigned w0 = (unsigned)ecol[tile0 + i] | ((unsigned)(r & 127) << 24);
        unsigned w1 = (unsigned)__float_as_int(eval[tile0 + i]);
        bkt[gbase[b] + off] = (long long)(((unsigned long long)w1 << 32) | w0);
    }
}

// phase 2: one block per bucket. Count rows -> scan -> scatter to exact-row
// CSR order within the bucket's own window (single-block L2 locality).
__global__ __launch_bounds__(512) void k_row_sort(
    const int* __restrict__ bucket_off, const long long* __restrict__ bkt,
    long long* __restrict__ csr, int* __restrict__ row_ptr)
{
    __shared__ int cnt[BROWS];
    __shared__ int cur[BROWS];
    const int t = threadIdx.x;
    const int b = blockIdx.x;
    const int start = bucket_off[b];
    const int end   = bucket_off[b + 1];
    const int n = end - start;

    if (t < BROWS) cnt[t] = 0;
    __syncthreads();
    for (int i = t; i < n; i += 512) {
        int w0 = ((const int2*)bkt)[start + i].x;
        atomicAdd(&cnt[(unsigned)w0 >> 24], 1);
    }
    __syncthreads();
    if (t < BROWS) cur[t] = cnt[t];
    __syncthreads();
    for (int off = 1; off < BROWS; off <<= 1) {
        int v = 0;
        if (t < BROWS && t >= off) v = cur[t - off];
        __syncthreads();
        if (t < BROWS) cur[t] += v;
        __syncthreads();
    }
    if (t < BROWS) {
        int excl = cur[t] - cnt[t];          // exclusive scan
        cur[t] = excl;                       // becomes cursor
        int row = b * BROWS + t;
        if (row < N_NODES) row_ptr[row] = start + excl;
    }
    __syncthreads();
    for (int i = t; i < n; i += 512) {
        long long ed = bkt[start + i];
        int lr = (int)((unsigned)ed >> 24);
        int p = atomicAdd(&cur[lr], 1);
        csr[start + p] = ed;
    }
}

// ---------------------------------------------------------------------------
// K2: CSR SpMM — one wave per row, register accumulation, bf16 gathers,
// 8 edges in flight per wave (r4 structure, deeper unroll).
// ---------------------------------------------------------------------------
__global__ __launch_bounds__(TPB) void k_spmm_csr_bf16(
    const int* __restrict__ row_ptr, const int2* __restrict__ csr,
    const unsigned* __restrict__ hb, float* __restrict__ neigh)
{
    int row = (int)((blockIdx.x * TPB + threadIdx.x) >> 6);
    if (row >= N_NODES) return;
    int lane = threadIdx.x & 63;

    int e   = row_ptr[row];
    int end = row_ptr[row + 1];

    float ax = 0.f, ay = 0.f;
    for (; e + 8 <= end; e += 8) {
        int2 c[8];
        #pragma unroll
        for (int k = 0; k < 8; k++) c[k] = csr[e + k];
        unsigned gv[8];
        #pragma unroll
        for (int k = 0; k < 8; k++)
            gv[k] = hb[(size_t)((unsigned)c[k].x & 0xFFFFFFu) * 64 + lane];
        #pragma unroll
        for (int k = 0; k < 8; k++) {
            float v = __int_as_float(c[k].y);
            ax += v * __uint_as_float(gv[k] << 16);
            ay += v * __uint_as_float(gv[k] & 0xFFFF0000u);
        }
    }
    for (; e < end; e++) {
        int2 c = csr[e];
        unsigned g = hb[(size_t)((unsigned)c.x & 0xFFFFFFu) * 64 + lane];
        float v = __int_as_float(c.y);
        ax += v * __uint_as_float(g << 16);
        ay += v * __uint_as_float(g & 0xFFFF0000u);
    }
    *((float2*)(neigh + (size_t)row * H) + lane) = make_float2(ax, ay);
}

// f32-gather variant (tier B: no hb buffer)
__global__ __launch_bounds__(TPB) void k_spmm_csr_f32(
    const int* __restrict__ row_ptr, const int2* __restrict__ csr,
    const float* __restrict__ h, float* __restrict__ neigh)
{
    int row = (int)((blockIdx.x * TPB + threadIdx.x) >> 6);
    if (row >= N_NODES) return;
    int lane = threadIdx.x & 63;
    int e   = row_ptr[row];
    int end = row_ptr[row + 1];
    float ax = 0.f, ay = 0.f;
    for (; e + 4 <= end; e += 4) {
        int2 c[4];
        #pragma unroll
        for (int k = 0; k < 4; k++) c[k] = csr[e + k];
        float2 gv[4];
        #pragma unroll
        for (int k = 0; k < 4; k++)
            gv[k] = *((const float2*)(h + (size_t)((unsigned)c[k].x & 0xFFFFFFu) * H) + lane);
        #pragma unroll
        for (int k = 0; k < 4; k++) {
            float v = __int_as_float(c[k].y);
            ax += v * gv[k].x;
            ay += v * gv[k].y;
        }
    }
    for (; e < end; e++) {
        int2 c = csr[e];
        float2 gv = *((const float2*)(h + (size_t)((unsigned)c.x & 0xFFFFFFu) * H) + lane);
        float v = __int_as_float(c.y);
        ax += v * gv.x;
        ay += v * gv.y;
    }
    *((float2*)(neigh + (size_t)row * H) + lane) = make_float2(ax, ay);
}

// Tier C fallback: atomic SpMM
__global__ __launch_bounds__(TPB) void k_spmm_atomic(
    const int* __restrict__ erow, const int* __restrict__ ecol,
    const float* __restrict__ eval, const float* __restrict__ h,
    float* __restrict__ neigh)
{
    unsigned int gid = blockIdx.x * TPB + threadIdx.x;
    int e = (int)(gid >> 5);
    if (e >= N_EDGES) return;
    int c = ((int)gid & 31) * 4;
    int col = ecol[e];
    int row = erow[e];
    float v = eval[e];
    const float4 hv = *(const float4*)(h + (size_t)col * H + c);
    float* dst = neigh + (size_t)row * H + c;
    unsafeAtomicAdd(dst + 0, v * hv.x);
    unsafeAtomicAdd(dst + 1, v * hv.y);
    unsafeAtomicAdd(dst + 2, v * hv.z);
    unsafeAtomicAdd(dst + 3, v * hv.w);
}

// ---------------------------------------------------------------------------
// Weight prep for the MFMA dense layers: per layer l,
//   Wt[c][k] = bf16( k<128 ? Wself[k][c] : Wneigh[k-128][c] )   [128][256]
//   bsum[c]  = bself[c] + bneigh[c]
// One GEMM of K=256 replaces the two K=128 GEMMs.
// ---------------------------------------------------------------------------
__global__ __launch_bounds__(256) void k_prep_w(
    const float* __restrict__ Wself, const float* __restrict__ bself,
    const float* __restrict__ Wneigh, const float* __restrict__ bneigh,
    unsigned short* __restrict__ Wt, float* __restrict__ bsum)
{
    const int l = blockIdx.x;
    const float* Ws = Wself  + (size_t)l * H * H;
    const float* Wn = Wneigh + (size_t)l * H * H;
    unsigned short* wt = Wt + (size_t)l * H * 256;
    for (int idx = threadIdx.x; idx < H * 256; idx += 256) {
        int c = idx >> 8;      // 0..127  (output col)
        int k = idx & 255;     // 0..255  (stacked K)
        float v = (k < H) ? Ws[(size_t)k * H + c] : Wn[(size_t)(k - H) * H + c];
        wt[(size_t)c * 256 + k] = (unsigned short)bf_rne(v);
    }
    if (threadIdx.x < H)
        bsum[l * H + threadIdx.x] = bself[l * H + threadIdx.x] + bneigh[l * H + threadIdx.x];
}

// ---------------------------------------------------------------------------
// K3 (MFMA): h += relu([h|neigh]_bf16 @ Wt^T + bsum), fused hb pack + pooling.
// 64 nodes/block, 4 waves; wave w owns rows w*16..w*16+15 x all 128 cols.
// A-frags from XOR-swizzled LDS (conflict-free ds_read_b128); B-frags from
// global Wt (L2-resident, 64 KB/layer). D-layout: col=lane&15,
// row=(lane>>4)*4+reg  [m89-verified]. K split in two phases (h then neigh)
// so the bf16 staging buffer stays at 16 KB (LDS total 58 KB < 64 KB limit).
// ---------------------------------------------------------------------------
__global__ __launch_bounds__(TPB) void k_layer_dense_mfma(
    const float* __restrict__ neigh,
    const unsigned short* __restrict__ Wt, const float* __restrict__ bsum,
    float* __restrict__ h, unsigned* __restrict__ hb,
    float* __restrict__ gout, int do_pool)
{
    __shared__ unsigned short xa[DBM * H];   // 16 KB, swizzled [64][128] bf16
    __shared__ float hold[DBM][132];         // 33 KB, padded f32 residual/out
    __shared__ float psum[8][H];             // 4 KB
    __shared__ float pmax[8][H];             // 4 KB
    const int tid  = threadIdx.x;
    const int base = blockIdx.x * DBM;
    const int wave = tid >> 6;
    const int lane = tid & 63;

    // ---- stage phase 1: h -> hold (f32) + xa (bf16, swizzled) ----
    #pragma unroll
    for (int i = 0; i < 8; i++) {
        int r  = i * 8 + (tid >> 5);
        int c4 = tid & 31;
        float4 hv = *(const float4*)(h + (size_t)(base + r) * H + c4 * 4);
        *(float4*)&hold[r][c4 * 4] = hv;
        unsigned lo = bf_rne(hv.x) | (bf_rne(hv.y) << 16);
        unsigned hi = bf_rne(hv.z) | (bf_rne(hv.w) << 16);
        unsigned boff = ((unsigned)r << 8) + ((unsigned)c4 << 3);
        boff ^= (unsigned)((r & 7) << 4);
        *(uint2*)((char*)xa + boff) = make_uint2(lo, hi);
    }
    __syncthreads();

    // ---- MFMA phase 1: k = 0..127 (h part) ----
    const int mrow = (wave << 4) + (lane & 15);
    const unsigned swz = (unsigned)((mrow & 7) << 4);
    f32x4 acc[8];
    #pragma unroll
    for (int ct = 0; ct < 8; ct++)
        #pragma unroll
        for (int j = 0; j < 4; j++) acc[ct][j] = 0.f;

    #pragma unroll
    for (int kt = 0; kt < 4; kt++) {
        unsigned aoff = (((unsigned)mrow << 8) +
                         (((unsigned)(kt << 5) + ((lane >> 4) << 3)) << 1)) ^ swz;
        bf16x8 af = *(const bf16x8*)((const char*)xa + aoff);
        #pragma unroll
        for (int ct = 0; ct < 8; ct++) {
            const unsigned short* bp = Wt + (size_t)((ct << 4) + (lane & 15)) * 256
                                          + (kt << 5) + ((lane >> 4) << 3);
            bf16x8 bf = *(const bf16x8*)bp;
            acc[ct] = __builtin_amdgcn_mfma_f32_16x16x32_bf16(af, bf, acc[ct], 0, 0, 0);
        }
    }
    __syncthreads();

    // ---- stage phase 2: neigh -> xa (bf16, swizzled) ----
    #pragma unroll
    for (int i = 0; i < 8; i++) {
        int r  = i * 8 + (tid >> 5);
        int c4 = tid & 31;
        float4 nv = *(const float4*)(neigh + (size_t)(base + r) * H + c4 * 4);
        unsigned lo = bf_rne(nv.x) | (bf_rne(nv.y) << 16);
        unsigned hi = bf_rne(nv.z) | (bf_rne(nv.w) << 16);
        unsigned boff = ((unsigned)r << 8) + ((unsigned)c4 << 3);
        boff ^= (unsigned)((r & 7) << 4);
        *(uint2*)((char*)xa + boff) = make_uint2(lo, hi);
    }
    __syncthreads();

    // ---- MFMA phase 2: k = 128..255 (neigh part) ----
    #pragma unroll
    for (int kt = 0; kt < 4; kt++) {
        unsigned aoff = (((unsigned)mrow << 8) +
                         (((unsigned)(kt << 5) + ((lane >> 4) << 3)) << 1)) ^ swz;
        bf16x8 af = *(const bf16x8*)((const char*)xa + aoff);
        #pragma unroll
        for (int ct = 0; ct < 8; ct++) {
            const unsigned short* bp = Wt + (size_t)((ct << 4) + (lane & 15)) * 256
                                          + 128 + (kt << 5) + ((lane >> 4) << 3);
            bf16x8 bf = *(const bf16x8*)bp;
            acc[ct] = __builtin_amdgcn_mfma_f32_16x16x32_bf16(af, bf, acc[ct], 0, 0, 0);
        }
    }

    // ---- epilogue: bias + relu + residual into hold ----
    #pragma unroll
    for (int ct = 0; ct < 8; ct++) {
        int col = (ct << 4) + (lane & 15);
        float bsv = bsum[col];
        #pragma unroll
        for (int r = 0; r < 4; r++) {
            int nl = (wave << 4) + ((lane >> 4) << 2) + r;
            float v = fmaxf(acc[ct][r] + bsv, 0.f);
            hold[nl][col] += v;
        }
    }
    __syncthreads();

    // ---- writeout: h f32 + optional hb bf16 + pooling partials ----
    float csum[4] = {0.f, 0.f, 0.f, 0.f};
    float cmax[4] = {0.f, 0.f, 0.f, 0.f};
    const int c4 = tid & 31;
    #pragma unroll
    for (int i = 0; i < 8; i++) {
        int r = i * 8 + (tid >> 5);
        float4 ov = *(const float4*)&hold[r][c4 * 4];
        *(float4*)(h + (size_t)(base + r) * H + c4 * 4) = ov;
        if (hb) {
            uint2 p;
            p.x = bf_rne(ov.x) | (bf_rne(ov.y) << 16);
            p.y = bf_rne(ov.z) | (bf_rne(ov.w) << 16);
            *(uint2*)(hb + (size_t)(base + r) * 64 + c4 * 2) = p;
        }
        if (do_pool) {
            csum[0] += ov.x; cmax[0] = fmaxf(cmax[0], ov.x);
            csum[1] += ov.y; cmax[1] = fmaxf(cmax[1], ov.y);
            csum[2] += ov.z; cmax[2] = fmaxf(cmax[2], ov.z);
            csum[3] += ov.w; cmax[3] = fmaxf(cmax[3], ov.w);
        }
    }

    if (do_pool) {
        const int grp = tid >> 5;
        #pragma unroll
        for (int j = 0; j < 4; j++) {
            psum[grp][c4 * 4 + j] = csum[j];
            pmax[grp][c4 * 4 + j] = cmax[j];
        }
        __syncthreads();
        if (tid < H) {
            float s = 0.f, m = 0.f;
            #pragma unroll
            for (int gix = 0; gix < 8; gix++) {
                s += psum[gix][tid];
                m = fmaxf(m, pmax[gix][tid]);
            }
            unsafeAtomicAdd(&gout[tid], s);
            atomicMax((int*)&gout[H + tid], __float_as_int(m));
        }
    }
}

// ---------------------------------------------------------------------------
// K3 fallback (f32 VALU) — used only when workspace lacks room for Wt.
// ---------------------------------------------------------------------------
__global__ __launch_bounds__(TPB) void k_layer_dense(
    const float* __restrict__ neigh,
    const float* __restrict__ Wself, const float* __restrict__ bself,
    const float* __restrict__ Wneigh, const float* __restrict__ bneigh,
    float* __restrict__ h, unsigned* __restrict__ hb,
    float* __restrict__ gout, int do_pool)
{
    __shared__ float h_lds[NPB][H];
    __shared__ float n_lds[NPB][H];
    __shared__ float psum[8][H];
    __shared__ float pmax[8][H];
    const int tid  = threadIdx.x;
    const int base = blockIdx.x * NPB;

    for (int idx = tid; idx < NPB * H / 4; idx += TPB) {
        int r = idx >> 5, c = (idx & 31) * 4;
        *(float4*)&h_lds[r][c] = *(const float4*)(h + (size_t)(base + r) * H + c);
        *(float4*)&n_lds[r][c] = *(const float4*)(neigh + (size_t)(base + r) * H + c);
    }
    __syncthreads();

    const int c0 = (tid & 31) * 4;
    const int r0 = (tid >> 5) * 4;
    const int grp = tid >> 5;

    float acc[4][4];
    #pragma unroll
    for (int i = 0; i < 4; i++)
        #pragma unroll
        for (int j = 0; j < 4; j++) acc[i][j] = 0.f;

    for (int k = 0; k < H; k += 4) {
        float4 a[4], b[4];
        #pragma unroll
        for (int i = 0; i < 4; i++) {
            a[i] = *(const float4*)&h_lds[r0 + i][k];
            b[i] = *(const float4*)&n_lds[r0 + i][k];
        }
        #pragma unroll
        for (int kk = 0; kk < 4; kk++) {
            float4 ws = *(const float4*)(Wself  + (size_t)(k + kk) * H + c0);
            float4 wn = *(const float4*)(Wneigh + (size_t)(k + kk) * H + c0);
            const float* wsf = (const float*)&ws;
            const float* wnf = (const float*)&wn;
            #pragma unroll
            for (int i = 0; i < 4; i++) {
                float av = ((const float*)&a[i])[kk];
                float bv = ((const float*)&b[i])[kk];
                #pragma unroll
                for (int j = 0; j < 4; j++)
                    acc[i][j] += av * wsf[j] + bv * wnf[j];
            }
        }
    }

    float4 bs = *(const float4*)(bself + c0);
    float4 bn = *(const float4*)(bneigh + c0);
    const float* bsf = (const float*)&bs;
    const float* bnf = (const float*)&bn;
    float csum[4] = {0.f, 0.f, 0.f, 0.f};
    float cmax[4] = {0.f, 0.f, 0.f, 0.f};
    #pragma unroll
    for (int i = 0; i < 4; i++) {
        int node = base + r0 + i;
        float4 out;
        float* of = (float*)&out;
        #pragma unroll
        for (int j = 0; j < 4; j++) {
            float v = fmaxf(acc[i][j] + bsf[j] + bnf[j], 0.f);
            of[j] = h_lds[r0 + i][c0 + j] + v;
            csum[j] += of[j];
            cmax[j] = fmaxf(cmax[j], of[j]);
        }
        *(float4*)(h + (size_t)node * H + c0) = out;
        if (hb) {
            uint2 p;
            p.x = bf_rne(of[0]) | (bf_rne(of[1]) << 16);
            p.y = bf_rne(of[2]) | (bf_rne(of[3]) << 16);
            *(uint2*)(hb + (size_t)node * 64 + (c0 >> 1)) = p;
        }
    }

    if (do_pool) {
        #pragma unroll
        for (int j = 0; j < 4; j++) {
            psum[grp][c0 + j] = csum[j];
            pmax[grp][c0 + j] = cmax[j];
        }
        __syncthreads();
        if (tid < H) {
            float s = 0.f, m = 0.f;
            #pragma unroll
            for (int gix = 0; gix < 8; gix++) {
                s += psum[gix][tid];
                m = fmaxf(m, pmax[gix][tid]);
            }
            unsafeAtomicAdd(&gout[tid], s);
            atomicMax((int*)&gout[H + tid], __float_as_int(m));
        }
    }
}

__global__ void k_finalize(float* __restrict__ g)
{
    int t = threadIdx.x;
    if (t < 128) g[t] *= (1.0f / (float)N_NODES);
}

// ---------------------------------------------------------------------------
extern "C" void kernel_launch(void* const* d_in, const int* in_sizes, int n_in,
                              void* d_out, int out_size, void* d_ws, size_t ws_size,
                              hipStream_t stream)
{
    const int*   midx  = (const int*)  d_in[0];
    const int*   widx  = (const int*)  d_in[1];
    const int*   tidx  = (const int*)  d_in[2];
    const float* cont  = (const float*)d_in[3];
    const int*   erow  = (const int*)  d_in[4];
    const int*   ecol  = (const int*)  d_in[5];
    const float* eval  = (const float*)d_in[6];
    const float* memb  = (const float*)d_in[7];
    const float* wemb  = (const float*)d_in[8];
    const float* temb  = (const float*)d_in[9];
    const float* W1    = (const float*)d_in[10];
    const float* b1    = (const float*)d_in[11];
    const float* W2    = (const float*)d_in[12];
    const float* b2    = (const float*)d_in[13];
    const float* Wself = (const float*)d_in[14];
    const float* bself = (const float*)d_in[15];
    const float* Wneigh= (const float*)d_in[16];
    const float* bneigh= (const float*)d_in[17];

    float* g = (float*)d_out;   // [256]
    float* h = g + 256;         // [N, H] lives in d_out

    // ---- workspace layout ----
    // neigh: 102.4 MB.  bkt (phase-1 buffer, 51.2 MB) ALIASES neigh: it is
    // fully consumed by k_row_sort before the first SpMM writes neigh.
    const size_t neigh_elems = (size_t)N_NODES * H;      // 25.6 M floats
    const size_t hb_elems    = (size_t)N_NODES * H / 2;  // 12.8 M u32

    float*     neigh = (float*)d_ws;
    long long* bkt   = (long long*)d_ws;                 // alias (see above)

    // tier A layout (with hb)
    unsigned*  hb    = (unsigned*)(neigh + neigh_elems);
    long long* csrA  = (long long*)(hb + hb_elems);
    // tier B layout (no hb)
    long long* csrB  = (long long*)(neigh + neigh_elems);

    const size_t tail_ints   = (size_t)(N_NODES + 2) + NBUCK + (NBUCK + 1) + NBUCK + 16;
    const size_t WT_BYTES    = (size_t)2 * H * 256 * sizeof(unsigned short); // 128 KB
    const size_t tierB_bytes = neigh_elems * 4 + (size_t)N_EDGES * 8 + tail_ints * 4;
    const size_t tierA_bytes = tierB_bytes + hb_elems * 4;
    const size_t tierM_bytes = tierA_bytes + 16 + 2 * H * sizeof(float) + WT_BYTES;
    const bool tierA = (ws_size >= tierA_bytes);
    const bool tierB = (ws_size >= tierB_bytes);
    const bool tierM = (ws_size >= tierM_bytes) && tierA;

    long long* csr = tierA ? csrA : csrB;
    int* row_ptr    = (int*)(csr + N_EDGES);   // N+2
    int* bhist      = row_ptr + N_NODES + 2;   // NBUCK
    int* bucket_off = bhist + NBUCK;           // NBUCK+1
    int* bucket_cur = bucket_off + NBUCK + 1;  // NBUCK

    float* bsum = (float*)(((uintptr_t)(bucket_cur + NBUCK) + 15) & ~(uintptr_t)15);
    unsigned short* Wt = (unsigned short*)(bsum + 2 * H);

    hipMemsetAsync(d_out, 0, 256 * sizeof(float), stream);

    k_input_mlp<<<N_NODES / NPB, TPB, 0, stream>>>(
        midx, widx, tidx, cont, memb, wemb, temb, W1, b1, W2, b2, h,
        tierA ? hb : nullptr);

    if (tierB) {
        if (tierM)
            k_prep_w<<<2, 256, 0, stream>>>(Wself, bself, Wneigh, bneigh, Wt, bsum);
        hipMemsetAsync(bhist, 0, NBUCK * sizeof(int), stream);
        k_bucket_hist<<<2048, 256, 0, stream>>>(erow, bhist);
        k_scan_buckets<<<1, 1024, 0, stream>>>(bhist, bucket_off, bucket_cur, row_ptr);
        k_bucket_sort<<<N_SORT_BLOCKS, SORT_TPB, 0, stream>>>(
            erow, ecol, eval, bucket_cur, bkt);
        k_row_sort<<<NBUCK, 512, 0, stream>>>(bucket_off, bkt, csr, row_ptr);

        for (int l = 0; l < 2; l++) {
            if (tierA) {
                k_spmm_csr_bf16<<<(N_NODES * 64 + TPB - 1) / TPB, TPB, 0, stream>>>(
                    row_ptr, (const int2*)csr, hb, neigh);
            } else {
                k_spmm_csr_f32<<<(N_NODES * 64 + TPB - 1) / TPB, TPB, 0, stream>>>(
                    row_ptr, (const int2*)csr, h, neigh);
            }
            if (tierM) {
                k_layer_dense_mfma<<<N_NODES / DBM, TPB, 0, stream>>>(
                    neigh, Wt + (size_t)l * H * 256, bsum + (size_t)l * H, h,
                    (l == 0) ? hb : nullptr, g, (l == 1) ? 1 : 0);
            } else {
                k_layer_dense<<<N_NODES / NPB, TPB, 0, stream>>>(
                    neigh, Wself + (size_t)l * H * H, bself + (size_t)l * H,
                    Wneigh + (size_t)l * H * H, bneigh + (size_t)l * H, h,
                    (tierA && l == 0) ? hb : nullptr, g, (l == 1) ? 1 : 0);
            }
        }
    } else {
        for (int l = 0; l < 2; l++) {
            hipMemsetAsync(neigh, 0, neigh_elems * sizeof(float), stream);
            unsigned int nthreads = (unsigned int)N_EDGES * 32u;
            k_spmm_atomic<<<nthreads / TPB, TPB, 0, stream>>>(erow, ecol, eval, h, neigh);
            k_layer_dense<<<N_NODES / NPB, TPB, 0, stream>>>(
                neigh, Wself + (size_t)l * H * H, bself + (size_t)l * H,
                Wneigh + (size_t)l * H * H, bneigh + (size_t)l * H, h,
                nullptr, g, (l == 1) ? 1 : 0);
        }
    }

    k_finalize<<<1, 128, 0, stream>>>(g);
}

// Round 5
// 1375.647 us; speedup vs baseline: 1.2181x; 1.0218x over previous
//
#include <hip/hip_runtime.h>

#define N_NODES 200000
#define N_EDGES 6400000
#define EMB 16
#define CONT 12
#define H 128
#define IN_DIM 60   // 3*EMB + CONT
#define NPB 32      // nodes per block for fallback dense kernel
#define TPB 256

#define BROWS 128                                    // rows per bucket
#define NBUCK ((N_NODES + BROWS - 1) / BROWS)        // 1563
#define SORT_TILE 16384
#define SORT_TPB 512
#define N_SORT_BLOCKS ((N_EDGES + SORT_TILE - 1) / SORT_TILE)  // 391

#define DBM 64      // nodes per block for the MFMA dense kernel

typedef __attribute__((ext_vector_type(8))) short  bf16x8;
typedef __attribute__((ext_vector_type(4))) float  f32x4;

// bf16 round-to-nearest-even pack helper (works for any finite f)
__device__ __forceinline__ unsigned bf_rne(float f) {
    unsigned u = __float_as_uint(f);
    return (u + 0x7FFFu + ((u >> 16) & 1u)) >> 16;
}

// ---------------------------------------------------------------------------
// K1: fused embedding gather + 2-layer input MLP + optional bf16 pack.
// 4x4 register blocking: FMA-bound, LDS broadcast reads. (proven r4)
// ---------------------------------------------------------------------------
__global__ __launch_bounds__(TPB) void k_input_mlp(
    const int* __restrict__ midx, const int* __restrict__ widx,
    const int* __restrict__ tidx, const float* __restrict__ cont,
    const float* __restrict__ memb, const float* __restrict__ wemb,
    const float* __restrict__ temb,
    const float* __restrict__ W1, const float* __restrict__ b1,
    const float* __restrict__ W2, const float* __restrict__ b2,
    float* __restrict__ h, unsigned* __restrict__ hb)
{
    __shared__ float x_lds[NPB][IN_DIM];
    __shared__ float h0_lds[NPB][H];
    const int tid  = threadIdx.x;
    const int base = blockIdx.x * NPB;

    for (int idx = tid; idx < NPB * IN_DIM; idx += TPB) {
        int n = idx / IN_DIM, k = idx % IN_DIM;
        int node = base + n;
        float v;
        if (k < 16)       v = memb[midx[node] * 16 + k];
        else if (k < 32)  v = wemb[widx[node] * 16 + (k - 16)];
        else if (k < 48)  v = temb[tidx[node] * 16 + (k - 32)];
        else              v = cont[(size_t)node * CONT + (k - 48)];
        x_lds[n][k] = v;
    }
    __syncthreads();

    const int c0 = (tid & 31) * 4;
    const int r0 = (tid >> 5) * 4;

    float acc[4][4];
    #pragma unroll
    for (int i = 0; i < 4; i++)
        #pragma unroll
        for (int j = 0; j < 4; j++) acc[i][j] = 0.f;

    for (int k = 0; k < IN_DIM; k += 4) {
        float4 a[4];
        #pragma unroll
        for (int i = 0; i < 4; i++) a[i] = *(const float4*)&x_lds[r0 + i][k];
        #pragma unroll
        for (int kk = 0; kk < 4; kk++) {
            float4 w = *(const float4*)(W1 + (size_t)(k + kk) * H + c0);
            const float* wf = (const float*)&w;
            #pragma unroll
            for (int i = 0; i < 4; i++) {
                float av = ((const float*)&a[i])[kk];
                #pragma unroll
                for (int j = 0; j < 4; j++)
                    acc[i][j] += av * wf[j];
            }
        }
    }
    {
        float4 bv = *(const float4*)(b1 + c0);
        const float* bf = (const float*)&bv;
        #pragma unroll
        for (int i = 0; i < 4; i++)
            #pragma unroll
            for (int j = 0; j < 4; j++)
                h0_lds[r0 + i][c0 + j] = fmaxf(acc[i][j] + bf[j], 0.f);
    }
    __syncthreads();

    #pragma unroll
    for (int i = 0; i < 4; i++)
        #pragma unroll
        for (int j = 0; j < 4; j++) acc[i][j] = 0.f;

    for (int k = 0; k < H; k += 4) {
        float4 a[4];
        #pragma unroll
        for (int i = 0; i < 4; i++) a[i] = *(const float4*)&h0_lds[r0 + i][k];
        #pragma unroll
        for (int kk = 0; kk < 4; kk++) {
            float4 w = *(const float4*)(W2 + (size_t)(k + kk) * H + c0);
            const float* wf = (const float*)&w;
            #pragma unroll
            for (int i = 0; i < 4; i++) {
                float av = ((const float*)&a[i])[kk];
                #pragma unroll
                for (int j = 0; j < 4; j++)
                    acc[i][j] += av * wf[j];
            }
        }
    }
    {
        float4 bv = *(const float4*)(b2 + c0);
        const float* bf = (const float*)&bv;
        #pragma unroll
        for (int i = 0; i < 4; i++) {
            int node = base + r0 + i;
            float4 out;
            float* of = (float*)&out;
            #pragma unroll
            for (int j = 0; j < 4; j++)
                of[j] = fmaxf(acc[i][j] + bf[j], 0.f);
            *(float4*)(h + (size_t)node * H + c0) = out;
            if (hb) {
                uint2 p;
                p.x = bf_rne(of[0]) | (bf_rne(of[1]) << 16);
                p.y = bf_rne(of[2]) | (bf_rne(of[3]) << 16);
                *(uint2*)(hb + (size_t)node * 64 + (c0 >> 1)) = p;
            }
        }
    }
}

// ---------------------------------------------------------------------------
// CSR build, two-phase write-combined:
//   hist -> scan -> phase1 bucket scatter (tile-segmented) -> phase2 row sort
// Entry format: low24 = col, bits24..31 = row-within-bucket, high32 = val.
// ---------------------------------------------------------------------------
__global__ __launch_bounds__(256) void k_bucket_hist(
    const int* __restrict__ erow, int* __restrict__ bhist)
{
    __shared__ int lh[NBUCK];
    for (int i = threadIdx.x; i < NBUCK; i += 256) lh[i] = 0;
    __syncthreads();
    for (int e = blockIdx.x * 256 + threadIdx.x; e < N_EDGES; e += gridDim.x * 256)
        atomicAdd(&lh[erow[e] >> 7], 1);
    __syncthreads();
    for (int i = threadIdx.x; i < NBUCK; i += 256) {
        int v = lh[i];
        if (v) atomicAdd(&bhist[i], v);
    }
}

__global__ __launch_bounds__(1024) void k_scan_buckets(
    const int* __restrict__ bhist, int* __restrict__ bucket_off,
    int* __restrict__ bucket_cur, int* __restrict__ row_ptr)
{
    __shared__ int s[1024];
    int t = threadIdx.x;
    int i0 = t * 2, i1 = t * 2 + 1;
    int v0 = (i0 < NBUCK) ? bhist[i0] : 0;
    int v1 = (i1 < NBUCK) ? bhist[i1] : 0;
    s[t] = v0 + v1;
    __syncthreads();
    for (int off = 1; off < 1024; off <<= 1) {
        int u = (t >= off) ? s[t - off] : 0;
        __syncthreads();
        s[t] += u;
        __syncthreads();
    }
    int base = (t > 0) ? s[t - 1] : 0;
    if (i0 < NBUCK) { bucket_off[i0] = base;      bucket_cur[i0] = base; }
    if (i1 < NBUCK) { bucket_off[i1] = base + v0; bucket_cur[i1] = base + v0; }
    if (t == 1023) {
        bucket_off[NBUCK] = s[1023];      // == N_EDGES
        row_ptr[N_NODES]  = s[1023];
    }
}

// phase 1: scatter to bucket granularity. Each tile reserves contiguous
// per-bucket segments so a segment's writes come from one block (one XCD):
// L2 write-combines lines (r5 evidence: exact-row scatter had 7.7x write amp).
__global__ __launch_bounds__(SORT_TPB) void k_bucket_sort(
    const int* __restrict__ erow, const int* __restrict__ ecol,
    const float* __restrict__ eval, int* __restrict__ bucket_cur,
    long long* __restrict__ bkt)
{
    __shared__ int hist[NBUCK];
    __shared__ int gbase[NBUCK];
    __shared__ int fcur[NBUCK];
    const int t = threadIdx.x;
    const int tile0 = blockIdx.x * SORT_TILE;
    const int nE = min(SORT_TILE, N_EDGES - tile0);

    for (int i = t; i < NBUCK; i += SORT_TPB) { hist[i] = 0; fcur[i] = 0; }
    __syncthreads();
    for (int i = t; i < nE; i += SORT_TPB)
        atomicAdd(&hist[erow[tile0 + i] >> 7], 1);
    __syncthreads();
    for (int i = t; i < NBUCK; i += SORT_TPB) {
        int c = hist[i];
        if (c) gbase[i] = atomicAdd(&bucket_cur[i], c);
    }
    __syncthreads();
    for (int i = t; i < nE; i += SORT_TPB) {
        int r = erow[tile0 + i];
        int b = r >> 7;
        int off = atomicAdd(&fcur[b], 1);
        unsigned w0 = (unsigned)ecol[tile0 + i] | ((unsigned)(r & 127) << 24);
        unsigned w1 = (unsigned)__float_as_int(eval[tile0 + i]);
        bkt[gbase[b] + off] = (long long)(((unsigned long long)w1 << 32) | w0);
    }
}

// phase 2: one block per bucket. Count rows -> scan -> scatter to exact-row
// CSR order within the bucket's own window (single-block L2 locality).
__global__ __launch_bounds__(512) void k_row_sort(
    const int* __restrict__ bucket_off, const long long* __restrict__ bkt,
    long long* __restrict__ csr, int* __restrict__ row_ptr)
{
    __shared__ int cnt[BROWS];
    __shared__ int cur[BROWS];
    const int t = threadIdx.x;
    const int b = blockIdx.x;
    const int start = bucket_off[b];
    const int end   = bucket_off[b + 1];
    const int n = end - start;

    if (t < BROWS) cnt[t] = 0;
    __syncthreads();
    for (int i = t; i < n; i += 512) {
        int w0 = ((const int2*)bkt)[start + i].x;
        atomicAdd(&cnt[(unsigned)w0 >> 24], 1);
    }
    __syncthreads();
    if (t < BROWS) cur[t] = cnt[t];
    __syncthreads();
    for (int off = 1; off < BROWS; off <<= 1) {
        int v = 0;
        if (t < BROWS && t >= off) v = cur[t - off];
        __syncthreads();
        if (t < BROWS) cur[t] += v;
        __syncthreads();
    }
    if (t < BROWS) {
        int excl = cur[t] - cnt[t];          // exclusive scan
        cur[t] = excl;                       // becomes cursor
        int row = b * BROWS + t;
        if (row < N_NODES) row_ptr[row] = start + excl;
    }
    __syncthreads();
    for (int i = t; i < n; i += 512) {
        long long ed = bkt[start + i];
        int lr = (int)((unsigned)ed >> 24);
        int p = atomicAdd(&cur[lr], 1);
        csr[start + p] = ed;
    }
}

// ---------------------------------------------------------------------------
// K2: CSR SpMM — one wave per row, quad-edge gather layout:
// lane = (sub = lane>>4, seg = lane&15). One uint4 load = 16 B of source row
// => a wave gathers FOUR full 256-B hb rows per instruction (4 edges).
// 4x unroll = 16 edges in flight. shfl_xor(16/32) reduce, lanes 0-15 write.
// ---------------------------------------------------------------------------
__global__ __launch_bounds__(TPB) void k_spmm_csr_bf16(
    const int* __restrict__ row_ptr, const int2* __restrict__ csr,
    const unsigned* __restrict__ hb, float* __restrict__ neigh)
{
    int row = (int)((blockIdx.x * TPB + threadIdx.x) >> 6);
    if (row >= N_NODES) return;
    const int lane = threadIdx.x & 63;
    const int sub  = lane >> 4;    // which edge within the quad
    const int seg  = lane & 15;    // which 16B segment of the 256B hb row
    const char* hbb = (const char*)hb;

    int e   = row_ptr[row];
    int end = row_ptr[row + 1];

    float acc[8];
    #pragma unroll
    for (int j = 0; j < 8; j++) acc[j] = 0.f;

    for (; e + 16 <= end; e += 16) {
        int2 c[4];
        #pragma unroll
        for (int q = 0; q < 4; q++) c[q] = csr[e + q * 4 + sub];
        uint4 g[4];
        #pragma unroll
        for (int q = 0; q < 4; q++)
            g[q] = *(const uint4*)(hbb +
                    (size_t)((unsigned)c[q].x & 0xFFFFFFu) * 256 + seg * 16);
        #pragma unroll
        for (int q = 0; q < 4; q++) {
            float v = __int_as_float(c[q].y);
            const unsigned* gu = (const unsigned*)&g[q];
            #pragma unroll
            for (int j = 0; j < 4; j++) {
                acc[2 * j]     += v * __uint_as_float(gu[j] << 16);
                acc[2 * j + 1] += v * __uint_as_float(gu[j] & 0xFFFF0000u);
            }
        }
    }
    for (; e < end; e += 4) {
        int idx = e + sub;
        int2 c = csr[(idx < end) ? idx : (end - 1)];
        float v = (idx < end) ? __int_as_float(c.y) : 0.f;
        uint4 g = *(const uint4*)(hbb +
                  (size_t)((unsigned)c.x & 0xFFFFFFu) * 256 + seg * 16);
        const unsigned* gu = (const unsigned*)&g;
        #pragma unroll
        for (int j = 0; j < 4; j++) {
            acc[2 * j]     += v * __uint_as_float(gu[j] << 16);
            acc[2 * j + 1] += v * __uint_as_float(gu[j] & 0xFFFF0000u);
        }
    }
    #pragma unroll
    for (int j = 0; j < 8; j++) {
        acc[j] += __shfl_xor(acc[j], 16);
        acc[j] += __shfl_xor(acc[j], 32);
    }
    if (sub == 0) {
        float* dst = neigh + (size_t)row * H + seg * 8;
        *(float4*)dst       = make_float4(acc[0], acc[1], acc[2], acc[3]);
        *(float4*)(dst + 4) = make_float4(acc[4], acc[5], acc[6], acc[7]);
    }
}

// f32-gather variant (tier B: no hb buffer)
__global__ __launch_bounds__(TPB) void k_spmm_csr_f32(
    const int* __restrict__ row_ptr, const int2* __restrict__ csr,
    const float* __restrict__ h, float* __restrict__ neigh)
{
    int row = (int)((blockIdx.x * TPB + threadIdx.x) >> 6);
    if (row >= N_NODES) return;
    int lane = threadIdx.x & 63;
    int e   = row_ptr[row];
    int end = row_ptr[row + 1];
    float ax = 0.f, ay = 0.f;
    for (; e + 4 <= end; e += 4) {
        int2 c[4];
        #pragma unroll
        for (int k = 0; k < 4; k++) c[k] = csr[e + k];
        float2 gv[4];
        #pragma unroll
        for (int k = 0; k < 4; k++)
            gv[k] = *((const float2*)(h + (size_t)((unsigned)c[k].x & 0xFFFFFFu) * H) + lane);
        #pragma unroll
        for (int k = 0; k < 4; k++) {
            float v = __int_as_float(c[k].y);
            ax += v * gv[k].x;
            ay += v * gv[k].y;
        }
    }
    for (; e < end; e++) {
        int2 c = csr[e];
        float2 gv = *((const float2*)(h + (size_t)((unsigned)c.x & 0xFFFFFFu) * H) + lane);
        float v = __int_as_float(c.y);
        ax += v * gv.x;
        ay += v * gv.y;
    }
    *((float2*)(neigh + (size_t)row * H) + lane) = make_float2(ax, ay);
}

// Tier C fallback: atomic SpMM
__global__ __launch_bounds__(TPB) void k_spmm_atomic(
    const int* __restrict__ erow, const int* __restrict__ ecol,
    const float* __restrict__ eval, const float* __restrict__ h,
    float* __restrict__ neigh)
{
    unsigned int gid = blockIdx.x * TPB + threadIdx.x;
    int e = (int)(gid >> 5);
    if (e >= N_EDGES) return;
    int c = ((int)gid & 31) * 4;
    int col = ecol[e];
    int row = erow[e];
    float v = eval[e];
    const float4 hv = *(const float4*)(h + (size_t)col * H + c);
    float* dst = neigh + (size_t)row * H + c;
    unsafeAtomicAdd(dst + 0, v * hv.x);
    unsafeAtomicAdd(dst + 1, v * hv.y);
    unsafeAtomicAdd(dst + 2, v * hv.z);
    unsafeAtomicAdd(dst + 3, v * hv.w);
}

// ---------------------------------------------------------------------------
// Weight prep for the MFMA dense layers: per layer l,
//   Wt[c][k] = bf16( k<128 ? Wself[k][c] : Wneigh[k-128][c] )   [128][256]
//   bsum[c]  = bself[c] + bneigh[c]
// One GEMM of K=256 replaces the two K=128 GEMMs.
// ---------------------------------------------------------------------------
__global__ __launch_bounds__(256) void k_prep_w(
    const float* __restrict__ Wself, const float* __restrict__ bself,
    const float* __restrict__ Wneigh, const float* __restrict__ bneigh,
    unsigned short* __restrict__ Wt, float* __restrict__ bsum)
{
    const int l = blockIdx.x;
    const float* Ws = Wself  + (size_t)l * H * H;
    const float* Wn = Wneigh + (size_t)l * H * H;
    unsigned short* wt = Wt + (size_t)l * H * 256;
    for (int idx = threadIdx.x; idx < H * 256; idx += 256) {
        int c = idx >> 8;      // 0..127  (output col)
        int k = idx & 255;     // 0..255  (stacked K)
        float v = (k < H) ? Ws[(size_t)k * H + c] : Wn[(size_t)(k - H) * H + c];
        wt[(size_t)c * 256 + k] = (unsigned short)bf_rne(v);
    }
    if (threadIdx.x < H)
        bsum[l * H + threadIdx.x] = bself[l * H + threadIdx.x] + bneigh[l * H + threadIdx.x];
}

// ---------------------------------------------------------------------------
// K3 (MFMA): h += relu([h|neigh]_bf16 @ Wt^T + bsum), fused hb pack + pooling.
// 64 nodes/block, 4 waves; wave w owns rows w*16..w*16+15 x all 128 cols.
// A-frags from XOR-swizzled LDS (conflict-free ds_read_b128); B-frags from
// global Wt (L2-resident, 64 KB/layer). D-layout: col=lane&15,
// row=(lane>>4)*4+reg  [m89-verified]. K split in two phases (h then neigh)
// so the bf16 staging buffer stays at 16 KB (LDS total 58 KB < 64 KB limit).
// ---------------------------------------------------------------------------
__global__ __launch_bounds__(TPB) void k_layer_dense_mfma(
    const float* __restrict__ neigh,
    const unsigned short* __restrict__ Wt, const float* __restrict__ bsum,
    float* __restrict__ h, unsigned* __restrict__ hb,
    float* __restrict__ gout, int do_pool)
{
    __shared__ unsigned short xa[DBM * H];   // 16 KB, swizzled [64][128] bf16
    __shared__ float hold[DBM][132];         // 33 KB, padded f32 residual/out
    __shared__ float psum[8][H];             // 4 KB
    __shared__ float pmax[8][H];             // 4 KB
    const int tid  = threadIdx.x;
    const int base = blockIdx.x * DBM;
    const int wave = tid >> 6;
    const int lane = tid & 63;

    // ---- stage phase 1: h -> hold (f32) + xa (bf16, swizzled) ----
    #pragma unroll
    for (int i = 0; i < 8; i++) {
        int r  = i * 8 + (tid >> 5);
        int c4 = tid & 31;
        float4 hv = *(const float4*)(h + (size_t)(base + r) * H + c4 * 4);
        *(float4*)&hold[r][c4 * 4] = hv;
        unsigned lo = bf_rne(hv.x) | (bf_rne(hv.y) << 16);
        unsigned hi = bf_rne(hv.z) | (bf_rne(hv.w) << 16);
        unsigned boff = ((unsigned)r << 8) + ((unsigned)c4 << 3);
        boff ^= (unsigned)((r & 7) << 4);
        *(uint2*)((char*)xa + boff) = make_uint2(lo, hi);
    }
    __syncthreads();

    // ---- MFMA phase 1: k = 0..127 (h part) ----
    const int mrow = (wave << 4) + (lane & 15);
    const unsigned swz = (unsigned)((mrow & 7) << 4);
    f32x4 acc[8];
    #pragma unroll
    for (int ct = 0; ct < 8; ct++)
        #pragma unroll
        for (int j = 0; j < 4; j++) acc[ct][j] = 0.f;

    #pragma unroll
    for (int kt = 0; kt < 4; kt++) {
        unsigned aoff = (((unsigned)mrow << 8) +
                         (((unsigned)(kt << 5) + ((lane >> 4) << 3)) << 1)) ^ swz;
        bf16x8 af = *(const bf16x8*)((const char*)xa + aoff);
        #pragma unroll
        for (int ct = 0; ct < 8; ct++) {
            const unsigned short* bp = Wt + (size_t)((ct << 4) + (lane & 15)) * 256
                                          + (kt << 5) + ((lane >> 4) << 3);
            bf16x8 bf = *(const bf16x8*)bp;
            acc[ct] = __builtin_amdgcn_mfma_f32_16x16x32_bf16(af, bf, acc[ct], 0, 0, 0);
        }
    }
    __syncthreads();

    // ---- stage phase 2: neigh -> xa (bf16, swizzled) ----
    #pragma unroll
    for (int i = 0; i < 8; i++) {
        int r  = i * 8 + (tid >> 5);
        int c4 = tid & 31;
        float4 nv = *(const float4*)(neigh + (size_t)(base + r) * H + c4 * 4);
        unsigned lo = bf_rne(nv.x) | (bf_rne(nv.y) << 16);
        unsigned hi = bf_rne(nv.z) | (bf_rne(nv.w) << 16);
        unsigned boff = ((unsigned)r << 8) + ((unsigned)c4 << 3);
        boff ^= (unsigned)((r & 7) << 4);
        *(uint2*)((char*)xa + boff) = make_uint2(lo, hi);
    }
    __syncthreads();

    // ---- MFMA phase 2: k = 128..255 (neigh part) ----
    #pragma unroll
    for (int kt = 0; kt < 4; kt++) {
        unsigned aoff = (((unsigned)mrow << 8) +
                         (((unsigned)(kt << 5) + ((lane >> 4) << 3)) << 1)) ^ swz;
        bf16x8 af = *(const bf16x8*)((const char*)xa + aoff);
        #pragma unroll
        for (int ct = 0; ct < 8; ct++) {
            const unsigned short* bp = Wt + (size_t)((ct << 4) + (lane & 15)) * 256
                                          + 128 + (kt << 5) + ((lane >> 4) << 3);
            bf16x8 bf = *(const bf16x8*)bp;
            acc[ct] = __builtin_amdgcn_mfma_f32_16x16x32_bf16(af, bf, acc[ct], 0, 0, 0);
        }
    }

    // ---- epilogue: bias + relu + residual into hold ----
    #pragma unroll
    for (int ct = 0; ct < 8; ct++) {
        int col = (ct << 4) + (lane & 15);
        float bsv = bsum[col];
        #pragma unroll
        for (int r = 0; r < 4; r++) {
            int nl = (wave << 4) + ((lane >> 4) << 2) + r;
            float v = fmaxf(acc[ct][r] + bsv, 0.f);
            hold[nl][col] += v;
        }
    }
    __syncthreads();

    // ---- writeout: h f32 + optional hb bf16 + pooling partials ----
    float csum[4] = {0.f, 0.f, 0.f, 0.f};
    float cmax[4] = {0.f, 0.f, 0.f, 0.f};
    const int c4 = tid & 31;
    #pragma unroll
    for (int i = 0; i < 8; i++) {
        int r = i * 8 + (tid >> 5);
        float4 ov = *(const float4*)&hold[r][c4 * 4];
        *(float4*)(h + (size_t)(base + r) * H + c4 * 4) = ov;
        if (hb) {
            uint2 p;
            p.x = bf_rne(ov.x) | (bf_rne(ov.y) << 16);
            p.y = bf_rne(ov.z) | (bf_rne(ov.w) << 16);
            *(uint2*)(hb + (size_t)(base + r) * 64 + c4 * 2) = p;
        }
        if (do_pool) {
            csum[0] += ov.x; cmax[0] = fmaxf(cmax[0], ov.x);
            csum[1] += ov.y; cmax[1] = fmaxf(cmax[1], ov.y);
            csum[2] += ov.z; cmax[2] = fmaxf(cmax[2], ov.z);
            csum[3] += ov.w; cmax[3] = fmaxf(cmax[3], ov.w);
        }
    }

    if (do_pool) {
        const int grp = tid >> 5;
        #pragma unroll
        for (int j = 0; j < 4; j++) {
            psum[grp][c4 * 4 + j] = csum[j];
            pmax[grp][c4 * 4 + j] = cmax[j];
        }
        __syncthreads();
        if (tid < H) {
            float s = 0.f, m = 0.f;
            #pragma unroll
            for (int gix = 0; gix < 8; gix++) {
                s += psum[gix][tid];
                m = fmaxf(m, pmax[gix][tid]);
            }
            unsafeAtomicAdd(&gout[tid], s);
            atomicMax((int*)&gout[H + tid], __float_as_int(m));
        }
    }
}

// ---------------------------------------------------------------------------
// K3 fallback (f32 VALU) — used only when workspace lacks room for Wt.
// ---------------------------------------------------------------------------
__global__ __launch_bounds__(TPB) void k_layer_dense(
    const float* __restrict__ neigh,
    const float* __restrict__ Wself, const float* __restrict__ bself,
    const float* __restrict__ Wneigh, const float* __restrict__ bneigh,
    float* __restrict__ h, unsigned* __restrict__ hb,
    float* __restrict__ gout, int do_pool)
{
    __shared__ float h_lds[NPB][H];
    __shared__ float n_lds[NPB][H];
    __shared__ float psum[8][H];
    __shared__ float pmax[8][H];
    const int tid  = threadIdx.x;
    const int base = blockIdx.x * NPB;

    for (int idx = tid; idx < NPB * H / 4; idx += TPB) {
        int r = idx >> 5, c = (idx & 31) * 4;
        *(float4*)&h_lds[r][c] = *(const float4*)(h + (size_t)(base + r) * H + c);
        *(float4*)&n_lds[r][c] = *(const float4*)(neigh + (size_t)(base + r) * H + c);
    }
    __syncthreads();

    const int c0 = (tid & 31) * 4;
    const int r0 = (tid >> 5) * 4;
    const int grp = tid >> 5;

    float acc[4][4];
    #pragma unroll
    for (int i = 0; i < 4; i++)
        #pragma unroll
        for (int j = 0; j < 4; j++) acc[i][j] = 0.f;

    for (int k = 0; k < H; k += 4) {
        float4 a[4], b[4];
        #pragma unroll
        for (int i = 0; i < 4; i++) {
            a[i] = *(const float4*)&h_lds[r0 + i][k];
            b[i] = *(const float4*)&n_lds[r0 + i][k];
        }
        #pragma unroll
        for (int kk = 0; kk < 4; kk++) {
            float4 ws = *(const float4*)(Wself  + (size_t)(k + kk) * H + c0);
            float4 wn = *(const float4*)(Wneigh + (size_t)(k + kk) * H + c0);
            const float* wsf = (const float*)&ws;
            const float* wnf = (const float*)&wn;
            #pragma unroll
            for (int i = 0; i < 4; i++) {
                float av = ((const float*)&a[i])[kk];
                float bv = ((const float*)&b[i])[kk];
                #pragma unroll
                for (int j = 0; j < 4; j++)
                    acc[i][j] += av * wsf[j] + bv * wnf[j];
            }
        }
    }

    float4 bs = *(const float4*)(bself + c0);
    float4 bn = *(const float4*)(bneigh + c0);
    const float* bsf = (const float*)&bs;
    const float* bnf = (const float*)&bn;
    float csum[4] = {0.f, 0.f, 0.f, 0.f};
    float cmax[4] = {0.f, 0.f, 0.f, 0.f};
    #pragma unroll
    for (int i = 0; i < 4; i++) {
        int node = base + r0 + i;
        float4 out;
        float* of = (float*)&out;
        #pragma unroll
        for (int j = 0; j < 4; j++) {
            float v = fmaxf(acc[i][j] + bsf[j] + bnf[j], 0.f);
            of[j] = h_lds[r0 + i][c0 + j] + v;
            csum[j] += of[j];
            cmax[j] = fmaxf(cmax[j], of[j]);
        }
        *(float4*)(h + (size_t)node * H + c0) = out;
        if (hb) {
            uint2 p;
            p.x = bf_rne(of[0]) | (bf_rne(of[1]) << 16);
            p.y = bf_rne(of[2]) | (bf_rne(of[3]) << 16);
            *(uint2*)(hb + (size_t)node * 64 + (c0 >> 1)) = p;
        }
    }

    if (do_pool) {
        #pragma unroll
        for (int j = 0; j < 4; j++) {
            psum[grp][c0 + j] = csum[j];
            pmax[grp][c0 + j] = cmax[j];
        }
        __syncthreads();
        if (tid < H) {
            float s = 0.f, m = 0.f;
            #pragma unroll
            for (int gix = 0; gix < 8; gix++) {
                s += psum[gix][tid];
                m = fmaxf(m, pmax[gix][tid]);
            }
            unsafeAtomicAdd(&gout[tid], s);
            atomicMax((int*)&gout[H + tid], __float_as_int(m));
        }
    }
}

__global__ void k_finalize(float* __restrict__ g)
{
    int t = threadIdx.x;
    if (t < 128) g[t] *= (1.0f / (float)N_NODES);
}

// ---------------------------------------------------------------------------
extern "C" void kernel_launch(void* const* d_in, const int* in_sizes, int n_in,
                              void* d_out, int out_size, void* d_ws, size_t ws_size,
                              hipStream_t stream)
{
    const int*   midx  = (const int*)  d_in[0];
    const int*   widx  = (const int*)  d_in[1];
    const int*   tidx  = (const int*)  d_in[2];
    const float* cont  = (const float*)d_in[3];
    const int*   erow  = (const int*)  d_in[4];
    const int*   ecol  = (const int*)  d_in[5];
    const float* eval  = (const float*)d_in[6];
    const float* memb  = (const float*)d_in[7];
    const float* wemb  = (const float*)d_in[8];
    const float* temb  = (const float*)d_in[9];
    const float* W1    = (const float*)d_in[10];
    const float* b1    = (const float*)d_in[11];
    const float* W2    = (const float*)d_in[12];
    const float* b2    = (const float*)d_in[13];
    const float* Wself = (const float*)d_in[14];
    const float* bself = (const float*)d_in[15];
    const float* Wneigh= (const float*)d_in[16];
    const float* bneigh= (const float*)d_in[17];

    float* g = (float*)d_out;   // [256]
    float* h = g + 256;         // [N, H] lives in d_out

    // ---- workspace layout ----
    // neigh: 102.4 MB.  bkt (phase-1 buffer, 51.2 MB) ALIASES neigh: it is
    // fully consumed by k_row_sort before the first SpMM writes neigh.
    const size_t neigh_elems = (size_t)N_NODES * H;      // 25.6 M floats
    const size_t hb_elems    = (size_t)N_NODES * H / 2;  // 12.8 M u32

    float*     neigh = (float*)d_ws;
    long long* bkt   = (long long*)d_ws;                 // alias (see above)

    // tier A layout (with hb)
    unsigned*  hb    = (unsigned*)(neigh + neigh_elems);
    long long* csrA  = (long long*)(hb + hb_elems);
    // tier B layout (no hb)
    long long* csrB  = (long long*)(neigh + neigh_elems);

    const size_t tail_ints   = (size_t)(N_NODES + 2) + NBUCK + (NBUCK + 1) + NBUCK + 16;
    const size_t WT_BYTES    = (size_t)2 * H * 256 * sizeof(unsigned short); // 128 KB
    const size_t tierB_bytes = neigh_elems * 4 + (size_t)N_EDGES * 8 + tail_ints * 4;
    const size_t tierA_bytes = tierB_bytes + hb_elems * 4;
    const size_t tierM_bytes = tierA_bytes + 16 + 2 * H * sizeof(float) + WT_BYTES;
    const bool tierA = (ws_size >= tierA_bytes);
    const bool tierB = (ws_size >= tierB_bytes);
    const bool tierM = (ws_size >= tierM_bytes) && tierA;

    long long* csr = tierA ? csrA : csrB;
    int* row_ptr    = (int*)(csr + N_EDGES);   // N+2
    int* bhist      = row_ptr + N_NODES + 2;   // NBUCK
    int* bucket_off = bhist + NBUCK;           // NBUCK+1
    int* bucket_cur = bucket_off + NBUCK + 1;  // NBUCK

    float* bsum = (float*)(((uintptr_t)(bucket_cur + NBUCK) + 15) & ~(uintptr_t)15);
    unsigned short* Wt = (unsigned short*)(bsum + 2 * H);

    hipMemsetAsync(d_out, 0, 256 * sizeof(float), stream);

    k_input_mlp<<<N_NODES / NPB, TPB, 0, stream>>>(
        midx, widx, tidx, cont, memb, wemb, temb, W1, b1, W2, b2, h,
        tierA ? hb : nullptr);

    if (tierB) {
        if (tierM)
            k_prep_w<<<2, 256, 0, stream>>>(Wself, bself, Wneigh, bneigh, Wt, bsum);
        hipMemsetAsync(bhist, 0, NBUCK * sizeof(int), stream);
        k_bucket_hist<<<2048, 256, 0, stream>>>(erow, bhist);
        k_scan_buckets<<<1, 1024, 0, stream>>>(bhist, bucket_off, bucket_cur, row_ptr);
        k_bucket_sort<<<N_SORT_BLOCKS, SORT_TPB, 0, stream>>>(
            erow, ecol, eval, bucket_cur, bkt);
        k_row_sort<<<NBUCK, 512, 0, stream>>>(bucket_off, bkt, csr, row_ptr);

        for (int l = 0; l < 2; l++) {
            if (tierA) {
                k_spmm_csr_bf16<<<(N_NODES * 64 + TPB - 1) / TPB, TPB, 0, stream>>>(
                    row_ptr, (const int2*)csr, hb, neigh);
            } else {
                k_spmm_csr_f32<<<(N_NODES * 64 + TPB - 1) / TPB, TPB, 0, stream>>>(
                    row_ptr, (const int2*)csr, h, neigh);
            }
            if (tierM) {
                k_layer_dense_mfma<<<N_NODES / DBM, TPB, 0, stream>>>(
                    neigh, Wt + (size_t)l * H * 256, bsum + (size_t)l * H, h,
                    (l == 0) ? hb : nullptr, g, (l == 1) ? 1 : 0);
            } else {
                k_layer_dense<<<N_NODES / NPB, TPB, 0, stream>>>(
                    neigh, Wself + (size_t)l * H * H, bself + (size_t)l * H,
                    Wneigh + (size_t)l * H * H, bneigh + (size_t)l * H, h,
                    (tierA && l == 0) ? hb : nullptr, g, (l == 1) ? 1 : 0);
            }
        }
    } else {
        for (int l = 0; l < 2; l++) {
            hipMemsetAsync(neigh, 0, neigh_elems * sizeof(float), stream);
            unsigned int nthreads = (unsigned int)N_EDGES * 32u;
            k_spmm_atomic<<<nthreads / TPB, TPB, 0, stream>>>(erow, ecol, eval, h, neigh);
            k_layer_dense<<<N_NODES / NPB, TPB, 0, stream>>>(
                neigh, Wself + (size_t)l * H * H, bself + (size_t)l * H,
                Wneigh + (size_t)l * H * H, bneigh + (size_t)l * H, h,
                nullptr, g, (l == 1) ? 1 : 0);
        }
    }

    k_finalize<<<1, 128, 0, stream>>>(g);
}

// Round 6
// 1325.571 us; speedup vs baseline: 1.2641x; 1.0378x over previous
//
#include <hip/hip_runtime.h>

#define N_NODES 200000
#define N_EDGES 6400000
#define EMB 16
#define CONT 12
#define H 128
#define IN_DIM 60   // 3*EMB + CONT
#define NPB 32      // nodes per block for fallback dense kernel
#define TPB 256

#define BROWS 128                                    // rows per bucket
#define NBUCK ((N_NODES + BROWS - 1) / BROWS)        // 1563
#define SORT_TILE 16384
#define SORT_TPB 512
#define N_SORT_BLOCKS ((N_EDGES + SORT_TILE - 1) / SORT_TILE)  // 391

#define DBM 64      // nodes per block for the MFMA kernels

typedef __attribute__((ext_vector_type(8))) short  bf16x8;
typedef __attribute__((ext_vector_type(4))) float  f32x4;

// bf16 round-to-nearest-even pack helper (works for any finite f)
__device__ __forceinline__ unsigned bf_rne(float f) {
    unsigned u = __float_as_uint(f);
    return (u + 0x7FFFu + ((u >> 16) & 1u)) >> 16;
}

// ---------------------------------------------------------------------------
// K1 fallback (f32 VALU) — used only when workspace lacks room for Wt tables.
// ---------------------------------------------------------------------------
__global__ __launch_bounds__(TPB) void k_input_mlp(
    const int* __restrict__ midx, const int* __restrict__ widx,
    const int* __restrict__ tidx, const float* __restrict__ cont,
    const float* __restrict__ memb, const float* __restrict__ wemb,
    const float* __restrict__ temb,
    const float* __restrict__ W1, const float* __restrict__ b1,
    const float* __restrict__ W2, const float* __restrict__ b2,
    float* __restrict__ h, unsigned* __restrict__ hb)
{
    __shared__ float x_lds[NPB][IN_DIM];
    __shared__ float h0_lds[NPB][H];
    const int tid  = threadIdx.x;
    const int base = blockIdx.x * NPB;

    for (int idx = tid; idx < NPB * IN_DIM; idx += TPB) {
        int n = idx / IN_DIM, k = idx % IN_DIM;
        int node = base + n;
        float v;
        if (k < 16)       v = memb[midx[node] * 16 + k];
        else if (k < 32)  v = wemb[widx[node] * 16 + (k - 16)];
        else if (k < 48)  v = temb[tidx[node] * 16 + (k - 32)];
        else              v = cont[(size_t)node * CONT + (k - 48)];
        x_lds[n][k] = v;
    }
    __syncthreads();

    const int c0 = (tid & 31) * 4;
    const int r0 = (tid >> 5) * 4;

    float acc[4][4];
    #pragma unroll
    for (int i = 0; i < 4; i++)
        #pragma unroll
        for (int j = 0; j < 4; j++) acc[i][j] = 0.f;

    for (int k = 0; k < IN_DIM; k += 4) {
        float4 a[4];
        #pragma unroll
        for (int i = 0; i < 4; i++) a[i] = *(const float4*)&x_lds[r0 + i][k];
        #pragma unroll
        for (int kk = 0; kk < 4; kk++) {
            float4 w = *(const float4*)(W1 + (size_t)(k + kk) * H + c0);
            const float* wf = (const float*)&w;
            #pragma unroll
            for (int i = 0; i < 4; i++) {
                float av = ((const float*)&a[i])[kk];
                #pragma unroll
                for (int j = 0; j < 4; j++)
                    acc[i][j] += av * wf[j];
            }
        }
    }
    {
        float4 bv = *(const float4*)(b1 + c0);
        const float* bf = (const float*)&bv;
        #pragma unroll
        for (int i = 0; i < 4; i++)
            #pragma unroll
            for (int j = 0; j < 4; j++)
                h0_lds[r0 + i][c0 + j] = fmaxf(acc[i][j] + bf[j], 0.f);
    }
    __syncthreads();

    #pragma unroll
    for (int i = 0; i < 4; i++)
        #pragma unroll
        for (int j = 0; j < 4; j++) acc[i][j] = 0.f;

    for (int k = 0; k < H; k += 4) {
        float4 a[4];
        #pragma unroll
        for (int i = 0; i < 4; i++) a[i] = *(const float4*)&h0_lds[r0 + i][k];
        #pragma unroll
        for (int kk = 0; kk < 4; kk++) {
            float4 w = *(const float4*)(W2 + (size_t)(k + kk) * H + c0);
            const float* wf = (const float*)&w;
            #pragma unroll
            for (int i = 0; i < 4; i++) {
                float av = ((const float*)&a[i])[kk];
                #pragma unroll
                for (int j = 0; j < 4; j++)
                    acc[i][j] += av * wf[j];
            }
        }
    }
    {
        float4 bv = *(const float4*)(b2 + c0);
        const float* bf = (const float*)&bv;
        #pragma unroll
        for (int i = 0; i < 4; i++) {
            int node = base + r0 + i;
            float4 out;
            float* of = (float*)&out;
            #pragma unroll
            for (int j = 0; j < 4; j++)
                of[j] = fmaxf(acc[i][j] + bf[j], 0.f);
            *(float4*)(h + (size_t)node * H + c0) = out;
            if (hb) {
                uint2 p;
                p.x = bf_rne(of[0]) | (bf_rne(of[1]) << 16);
                p.y = bf_rne(of[2]) | (bf_rne(of[3]) << 16);
                *(uint2*)(hb + (size_t)node * 64 + (c0 >> 1)) = p;
            }
        }
    }
}

// ---------------------------------------------------------------------------
// K1 (MFMA): h = relu(relu(x@W1+b1)@W2+b2); fused embedding gather, bf16
// MFMA for both layers (K=64 padded, then K=128), fused hb pack.
// Same wave/D-layout/swizzle structure as k_layer_dense_mfma.
// ---------------------------------------------------------------------------
__global__ __launch_bounds__(TPB) void k_input_mlp_mfma(
    const int* __restrict__ midx, const int* __restrict__ widx,
    const int* __restrict__ tidx, const float* __restrict__ cont,
    const float* __restrict__ memb, const float* __restrict__ wemb,
    const float* __restrict__ temb,
    const unsigned short* __restrict__ W1t, const float* __restrict__ b1,
    const unsigned short* __restrict__ W2t, const float* __restrict__ b2,
    float* __restrict__ h, unsigned* __restrict__ hb)
{
    __shared__ unsigned short xa[DBM * 64];   // 8 KB  swizzled [64][64] bf16 (x)
    __shared__ unsigned short xb[DBM * H];    // 16 KB swizzled [64][128] bf16 (h0)
    __shared__ float hold[DBM][132];          // 33 KB padded f32 scratch
    const int tid  = threadIdx.x;
    const int base = blockIdx.x * DBM;
    const int wave = tid >> 6;
    const int lane = tid & 63;

    // ---- stage x -> xa (bf16, swizzled; cols 60..63 zero-pad) ----
    for (int idx = tid; idx < DBM * 16; idx += TPB) {
        int r  = idx >> 4;          // node within block
        int g8 = idx & 15;          // 8-byte granule = cols g8*4..g8*4+3
        int node = base + r;
        float v[4];
        #pragma unroll
        for (int j = 0; j < 4; j++) {
            int k = g8 * 4 + j;
            float x;
            if (k < 16)       x = memb[midx[node] * 16 + k];
            else if (k < 32)  x = wemb[widx[node] * 16 + (k - 16)];
            else if (k < 48)  x = temb[tidx[node] * 16 + (k - 32)];
            else if (k < 60)  x = cont[(size_t)node * CONT + (k - 48)];
            else              x = 0.f;
            v[j] = x;
        }
        unsigned lo = bf_rne(v[0]) | (bf_rne(v[1]) << 16);
        unsigned hi = bf_rne(v[2]) | (bf_rne(v[3]) << 16);
        unsigned boff = ((unsigned)r << 7) + ((unsigned)g8 << 3);
        boff ^= (unsigned)((r & 7) << 4);
        *(uint2*)((char*)xa + boff) = make_uint2(lo, hi);
    }
    __syncthreads();

    const int mrow = (wave << 4) + (lane & 15);
    const unsigned swz = (unsigned)((mrow & 7) << 4);

    // ---- MFMA layer 1: K=64 ----
    f32x4 acc[8];
    #pragma unroll
    for (int ct = 0; ct < 8; ct++)
        #pragma unroll
        for (int j = 0; j < 4; j++) acc[ct][j] = 0.f;

    #pragma unroll
    for (int kt = 0; kt < 2; kt++) {
        unsigned k0 = (unsigned)(kt << 5) + ((lane >> 4) << 3);
        unsigned aoff = (((unsigned)mrow << 7) + (k0 << 1)) ^ swz;
        bf16x8 af = *(const bf16x8*)((const char*)xa + aoff);
        #pragma unroll
        for (int ct = 0; ct < 8; ct++) {
            const unsigned short* bp = W1t + (size_t)((ct << 4) + (lane & 15)) * 64 + k0;
            bf16x8 bf = *(const bf16x8*)bp;
            acc[ct] = __builtin_amdgcn_mfma_f32_16x16x32_bf16(af, bf, acc[ct], 0, 0, 0);
        }
    }
    // epilogue: h0 = relu(acc + b1) -> hold
    #pragma unroll
    for (int ct = 0; ct < 8; ct++) {
        int col = (ct << 4) + (lane & 15);
        float bv = b1[col];
        #pragma unroll
        for (int r = 0; r < 4; r++) {
            int nl = (wave << 4) + ((lane >> 4) << 2) + r;
            hold[nl][col] = fmaxf(acc[ct][r] + bv, 0.f);
        }
    }
    __syncthreads();

    // ---- restage h0 -> xb (bf16, swizzled) ----
    #pragma unroll
    for (int i = 0; i < 8; i++) {
        int r  = i * 8 + (tid >> 5);
        int c4 = tid & 31;
        float4 hv = *(const float4*)&hold[r][c4 * 4];
        unsigned lo = bf_rne(hv.x) | (bf_rne(hv.y) << 16);
        unsigned hi = bf_rne(hv.z) | (bf_rne(hv.w) << 16);
        unsigned boff = ((unsigned)r << 8) + ((unsigned)c4 << 3);
        boff ^= (unsigned)((r & 7) << 4);
        *(uint2*)((char*)xb + boff) = make_uint2(lo, hi);
    }
    __syncthreads();

    // ---- MFMA layer 2: K=128 ----
    #pragma unroll
    for (int ct = 0; ct < 8; ct++)
        #pragma unroll
        for (int j = 0; j < 4; j++) acc[ct][j] = 0.f;

    #pragma unroll
    for (int kt = 0; kt < 4; kt++) {
        unsigned aoff = (((unsigned)mrow << 8) +
                         (((unsigned)(kt << 5) + ((lane >> 4) << 3)) << 1)) ^ swz;
        bf16x8 af = *(const bf16x8*)((const char*)xb + aoff);
        #pragma unroll
        for (int ct = 0; ct < 8; ct++) {
            const unsigned short* bp = W2t + (size_t)((ct << 4) + (lane & 15)) * 128
                                           + (kt << 5) + ((lane >> 4) << 3);
            bf16x8 bf = *(const bf16x8*)bp;
            acc[ct] = __builtin_amdgcn_mfma_f32_16x16x32_bf16(af, bf, acc[ct], 0, 0, 0);
        }
    }
    __syncthreads();   // all reads of hold (restage) done before overwrite

    // epilogue: h = relu(acc + b2) -> hold
    #pragma unroll
    for (int ct = 0; ct < 8; ct++) {
        int col = (ct << 4) + (lane & 15);
        float bv = b2[col];
        #pragma unroll
        for (int r = 0; r < 4; r++) {
            int nl = (wave << 4) + ((lane >> 4) << 2) + r;
            hold[nl][col] = fmaxf(acc[ct][r] + bv, 0.f);
        }
    }
    __syncthreads();

    // ---- writeout: h f32 + hb bf16 pack ----
    #pragma unroll
    for (int i = 0; i < 8; i++) {
        int r  = i * 8 + (tid >> 5);
        int c4 = tid & 31;
        float4 ov = *(const float4*)&hold[r][c4 * 4];
        *(float4*)(h + (size_t)(base + r) * H + c4 * 4) = ov;
        if (hb) {
            uint2 p;
            p.x = bf_rne(ov.x) | (bf_rne(ov.y) << 16);
            p.y = bf_rne(ov.z) | (bf_rne(ov.w) << 16);
            *(uint2*)(hb + (size_t)(base + r) * 64 + c4 * 2) = p;
        }
    }
}

// ---------------------------------------------------------------------------
// CSR build, two-phase write-combined:
//   hist -> scan -> phase1 bucket scatter (tile-segmented) -> phase2 row sort
// Entry format: low24 = col, bits24..31 = row-within-bucket, high32 = val.
// ---------------------------------------------------------------------------
__global__ __launch_bounds__(256) void k_bucket_hist(
    const int* __restrict__ erow, int* __restrict__ bhist)
{
    __shared__ int lh[NBUCK];
    for (int i = threadIdx.x; i < NBUCK; i += 256) lh[i] = 0;
    __syncthreads();
    for (int e = blockIdx.x * 256 + threadIdx.x; e < N_EDGES; e += gridDim.x * 256)
        atomicAdd(&lh[erow[e] >> 7], 1);
    __syncthreads();
    for (int i = threadIdx.x; i < NBUCK; i += 256) {
        int v = lh[i];
        if (v) atomicAdd(&bhist[i], v);
    }
}

__global__ __launch_bounds__(1024) void k_scan_buckets(
    const int* __restrict__ bhist, int* __restrict__ bucket_off,
    int* __restrict__ bucket_cur, int* __restrict__ row_ptr)
{
    __shared__ int s[1024];
    int t = threadIdx.x;
    int i0 = t * 2, i1 = t * 2 + 1;
    int v0 = (i0 < NBUCK) ? bhist[i0] : 0;
    int v1 = (i1 < NBUCK) ? bhist[i1] : 0;
    s[t] = v0 + v1;
    __syncthreads();
    for (int off = 1; off < 1024; off <<= 1) {
        int u = (t >= off) ? s[t - off] : 0;
        __syncthreads();
        s[t] += u;
        __syncthreads();
    }
    int base = (t > 0) ? s[t - 1] : 0;
    if (i0 < NBUCK) { bucket_off[i0] = base;      bucket_cur[i0] = base; }
    if (i1 < NBUCK) { bucket_off[i1] = base + v0; bucket_cur[i1] = base + v0; }
    if (t == 1023) {
        bucket_off[NBUCK] = s[1023];      // == N_EDGES
        row_ptr[N_NODES]  = s[1023];
    }
}

// phase 1: scatter to bucket granularity. Each tile reserves contiguous
// per-bucket segments so a segment's writes come from one block (one XCD):
// L2 write-combines lines (r5 evidence: exact-row scatter had 7.7x write amp).
__global__ __launch_bounds__(SORT_TPB) void k_bucket_sort(
    const int* __restrict__ erow, const int* __restrict__ ecol,
    const float* __restrict__ eval, int* __restrict__ bucket_cur,
    long long* __restrict__ bkt)
{
    __shared__ int hist[NBUCK];
    __shared__ int gbase[NBUCK];
    __shared__ int fcur[NBUCK];
    const int t = threadIdx.x;
    const int tile0 = blockIdx.x * SORT_TILE;
    const int nE = min(SORT_TILE, N_EDGES - tile0);

    for (int i = t; i < NBUCK; i += SORT_TPB) { hist[i] = 0; fcur[i] = 0; }
    __syncthreads();
    for (int i = t; i < nE; i += SORT_TPB)
        atomicAdd(&hist[erow[tile0 + i] >> 7], 1);
    __syncthreads();
    for (int i = t; i < NBUCK; i += SORT_TPB) {
        int c = hist[i];
        if (c) gbase[i] = atomicAdd(&bucket_cur[i], c);
    }
    __syncthreads();
    for (int i = t; i < nE; i += SORT_TPB) {
        int r = erow[tile0 + i];
        int b = r >> 7;
        int off = atomicAdd(&fcur[b], 1);
        unsigned w0 = (unsigned)ecol[tile0 + i] | ((unsigned)(r & 127) << 24);
        unsigned w1 = (unsigned)__float_as_int(eval[tile0 + i]);
        bkt[gbase[b] + off] = (long long)(((unsigned long long)w1 << 32) | w0);
    }
}

// phase 2: one block per bucket. Count rows -> scan -> scatter to exact-row
// CSR order within the bucket's own window (single-block L2 locality).
__global__ __launch_bounds__(512) void k_row_sort(
    const int* __restrict__ bucket_off, const long long* __restrict__ bkt,
    long long* __restrict__ csr, int* __restrict__ row_ptr)
{
    __shared__ int cnt[BROWS];
    __shared__ int cur[BROWS];
    const int t = threadIdx.x;
    const int b = blockIdx.x;
    const int start = bucket_off[b];
    const int end   = bucket_off[b + 1];
    const int n = end - start;

    if (t < BROWS) cnt[t] = 0;
    __syncthreads();
    for (int i = t; i < n; i += 512) {
        int w0 = ((const int2*)bkt)[start + i].x;
        atomicAdd(&cnt[(unsigned)w0 >> 24], 1);
    }
    __syncthreads();
    if (t < BROWS) cur[t] = cnt[t];
    __syncthreads();
    for (int off = 1; off < BROWS; off <<= 1) {
        int v = 0;
        if (t < BROWS && t >= off) v = cur[t - off];
        __syncthreads();
        if (t < BROWS) cur[t] += v;
        __syncthreads();
    }
    if (t < BROWS) {
        int excl = cur[t] - cnt[t];          // exclusive scan
        cur[t] = excl;                       // becomes cursor
        int row = b * BROWS + t;
        if (row < N_NODES) row_ptr[row] = start + excl;
    }
    __syncthreads();
    for (int i = t; i < n; i += 512) {
        long long ed = bkt[start + i];
        int lr = (int)((unsigned)ed >> 24);
        int p = atomicAdd(&cur[lr], 1);
        csr[start + p] = ed;
    }
}

// ---------------------------------------------------------------------------
// K2: CSR SpMM — one wave per row, quad-edge gather layout:
// lane = (sub = lane>>4, seg = lane&15). One uint4 load = 16 B of source row
// => a wave gathers FOUR full 256-B hb rows per instruction (4 edges).
// 4x unroll = 16 edges in flight. shfl_xor(16/32) reduce, lanes 0-15 write.
// ---------------------------------------------------------------------------
__global__ __launch_bounds__(TPB) void k_spmm_csr_bf16(
    const int* __restrict__ row_ptr, const int2* __restrict__ csr,
    const unsigned* __restrict__ hb, float* __restrict__ neigh)
{
    int row = (int)((blockIdx.x * TPB + threadIdx.x) >> 6);
    if (row >= N_NODES) return;
    const int lane = threadIdx.x & 63;
    const int sub  = lane >> 4;    // which edge within the quad
    const int seg  = lane & 15;    // which 16B segment of the 256B hb row
    const char* hbb = (const char*)hb;

    int e   = row_ptr[row];
    int end = row_ptr[row + 1];

    float acc[8];
    #pragma unroll
    for (int j = 0; j < 8; j++) acc[j] = 0.f;

    for (; e + 16 <= end; e += 16) {
        int2 c[4];
        #pragma unroll
        for (int q = 0; q < 4; q++) c[q] = csr[e + q * 4 + sub];
        uint4 g[4];
        #pragma unroll
        for (int q = 0; q < 4; q++)
            g[q] = *(const uint4*)(hbb +
                    (size_t)((unsigned)c[q].x & 0xFFFFFFu) * 256 + seg * 16);
        #pragma unroll
        for (int q = 0; q < 4; q++) {
            float v = __int_as_float(c[q].y);
            const unsigned* gu = (const unsigned*)&g[q];
            #pragma unroll
            for (int j = 0; j < 4; j++) {
                acc[2 * j]     += v * __uint_as_float(gu[j] << 16);
                acc[2 * j + 1] += v * __uint_as_float(gu[j] & 0xFFFF0000u);
            }
        }
    }
    for (; e < end; e += 4) {
        int idx = e + sub;
        int2 c = csr[(idx < end) ? idx : (end - 1)];
        float v = (idx < end) ? __int_as_float(c.y) : 0.f;
        uint4 g = *(const uint4*)(hbb +
                  (size_t)((unsigned)c.x & 0xFFFFFFu) * 256 + seg * 16);
        const unsigned* gu = (const unsigned*)&g;
        #pragma unroll
        for (int j = 0; j < 4; j++) {
            acc[2 * j]     += v * __uint_as_float(gu[j] << 16);
            acc[2 * j + 1] += v * __uint_as_float(gu[j] & 0xFFFF0000u);
        }
    }
    #pragma unroll
    for (int j = 0; j < 8; j++) {
        acc[j] += __shfl_xor(acc[j], 16);
        acc[j] += __shfl_xor(acc[j], 32);
    }
    if (sub == 0) {
        float* dst = neigh + (size_t)row * H + seg * 8;
        *(float4*)dst       = make_float4(acc[0], acc[1], acc[2], acc[3]);
        *(float4*)(dst + 4) = make_float4(acc[4], acc[5], acc[6], acc[7]);
    }
}

// f32-gather variant (tier B: no hb buffer)
__global__ __launch_bounds__(TPB) void k_spmm_csr_f32(
    const int* __restrict__ row_ptr, const int2* __restrict__ csr,
    const float* __restrict__ h, float* __restrict__ neigh)
{
    int row = (int)((blockIdx.x * TPB + threadIdx.x) >> 6);
    if (row >= N_NODES) return;
    int lane = threadIdx.x & 63;
    int e   = row_ptr[row];
    int end = row_ptr[row + 1];
    float ax = 0.f, ay = 0.f;
    for (; e + 4 <= end; e += 4) {
        int2 c[4];
        #pragma unroll
        for (int k = 0; k < 4; k++) c[k] = csr[e + k];
        float2 gv[4];
        #pragma unroll
        for (int k = 0; k < 4; k++)
            gv[k] = *((const float2*)(h + (size_t)((unsigned)c[k].x & 0xFFFFFFu) * H) + lane);
        #pragma unroll
        for (int k = 0; k < 4; k++) {
            float v = __int_as_float(c[k].y);
            ax += v * gv[k].x;
            ay += v * gv[k].y;
        }
    }
    for (; e < end; e++) {
        int2 c = csr[e];
        float2 gv = *((const float2*)(h + (size_t)((unsigned)c.x & 0xFFFFFFu) * H) + lane);
        float v = __int_as_float(c.y);
        ax += v * gv.x;
        ay += v * gv.y;
    }
    *((float2*)(neigh + (size_t)row * H) + lane) = make_float2(ax, ay);
}

// Tier C fallback: atomic SpMM
__global__ __launch_bounds__(TPB) void k_spmm_atomic(
    const int* __restrict__ erow, const int* __restrict__ ecol,
    const float* __restrict__ eval, const float* __restrict__ h,
    float* __restrict__ neigh)
{
    unsigned int gid = blockIdx.x * TPB + threadIdx.x;
    int e = (int)(gid >> 5);
    if (e >= N_EDGES) return;
    int c = ((int)gid & 31) * 4;
    int col = ecol[e];
    int row = erow[e];
    float v = eval[e];
    const float4 hv = *(const float4*)(h + (size_t)col * H + c);
    float* dst = neigh + (size_t)row * H + c;
    unsafeAtomicAdd(dst + 0, v * hv.x);
    unsafeAtomicAdd(dst + 1, v * hv.y);
    unsafeAtomicAdd(dst + 2, v * hv.z);
    unsafeAtomicAdd(dst + 3, v * hv.w);
}

// ---------------------------------------------------------------------------
// Weight prep: blocks 0,1 -> layer-l dense Wt [128][256] + bsum;
//              block 2    -> input-MLP W1t [128][64] (K pad 60->64) + W2t [128][128]
// ---------------------------------------------------------------------------
__global__ __launch_bounds__(256) void k_prep_w(
    const float* __restrict__ Wself, const float* __restrict__ bself,
    const float* __restrict__ Wneigh, const float* __restrict__ bneigh,
    const float* __restrict__ W1, const float* __restrict__ W2,
    unsigned short* __restrict__ Wt, float* __restrict__ bsum,
    unsigned short* __restrict__ W1t, unsigned short* __restrict__ W2t)
{
    const int l = blockIdx.x;
    if (l < 2) {
        const float* Ws = Wself  + (size_t)l * H * H;
        const float* Wn = Wneigh + (size_t)l * H * H;
        unsigned short* wt = Wt + (size_t)l * H * 256;
        for (int idx = threadIdx.x; idx < H * 256; idx += 256) {
            int c = idx >> 8;      // 0..127  (output col)
            int k = idx & 255;     // 0..255  (stacked K)
            float v = (k < H) ? Ws[(size_t)k * H + c] : Wn[(size_t)(k - H) * H + c];
            wt[(size_t)c * 256 + k] = (unsigned short)bf_rne(v);
        }
        if (threadIdx.x < H)
            bsum[l * H + threadIdx.x] = bself[l * H + threadIdx.x] + bneigh[l * H + threadIdx.x];
    } else {
        for (int idx = threadIdx.x; idx < H * 64; idx += 256) {
            int c = idx >> 6;      // 0..127
            int k = idx & 63;      // 0..63
            float v = (k < IN_DIM) ? W1[(size_t)k * H + c] : 0.f;
            W1t[(size_t)c * 64 + k] = (unsigned short)bf_rne(v);
        }
        for (int idx = threadIdx.x; idx < H * H; idx += 256) {
            int c = idx >> 7;      // 0..127
            int k = idx & 127;     // 0..127
            W2t[(size_t)c * 128 + k] = (unsigned short)bf_rne(W2[(size_t)k * H + c]);
        }
    }
}

// ---------------------------------------------------------------------------
// K3 (MFMA): h += relu([h|neigh]_bf16 @ Wt^T + bsum), fused hb pack + pooling.
// 64 nodes/block, 4 waves; wave w owns rows w*16..w*16+15 x all 128 cols.
// A-frags from XOR-swizzled LDS (conflict-free ds_read_b128); B-frags from
// global Wt (L2-resident, 64 KB/layer). D-layout: col=lane&15,
// row=(lane>>4)*4+reg  [m89-verified]. K split in two phases (h then neigh).
// ---------------------------------------------------------------------------
__global__ __launch_bounds__(TPB) void k_layer_dense_mfma(
    const float* __restrict__ neigh,
    const unsigned short* __restrict__ Wt, const float* __restrict__ bsum,
    float* __restrict__ h, unsigned* __restrict__ hb,
    float* __restrict__ gout, int do_pool)
{
    __shared__ unsigned short xa[DBM * H];   // 16 KB, swizzled [64][128] bf16
    __shared__ float hold[DBM][132];         // 33 KB, padded f32 residual/out
    __shared__ float psum[8][H];             // 4 KB
    __shared__ float pmax[8][H];             // 4 KB
    const int tid  = threadIdx.x;
    const int base = blockIdx.x * DBM;
    const int wave = tid >> 6;
    const int lane = tid & 63;

    // ---- stage phase 1: h -> hold (f32) + xa (bf16, swizzled) ----
    #pragma unroll
    for (int i = 0; i < 8; i++) {
        int r  = i * 8 + (tid >> 5);
        int c4 = tid & 31;
        float4 hv = *(const float4*)(h + (size_t)(base + r) * H + c4 * 4);
        *(float4*)&hold[r][c4 * 4] = hv;
        unsigned lo = bf_rne(hv.x) | (bf_rne(hv.y) << 16);
        unsigned hi = bf_rne(hv.z) | (bf_rne(hv.w) << 16);
        unsigned boff = ((unsigned)r << 8) + ((unsigned)c4 << 3);
        boff ^= (unsigned)((r & 7) << 4);
        *(uint2*)((char*)xa + boff) = make_uint2(lo, hi);
    }
    __syncthreads();

    // ---- MFMA phase 1: k = 0..127 (h part) ----
    const int mrow = (wave << 4) + (lane & 15);
    const unsigned swz = (unsigned)((mrow & 7) << 4);
    f32x4 acc[8];
    #pragma unroll
    for (int ct = 0; ct < 8; ct++)
        #pragma unroll
        for (int j = 0; j < 4; j++) acc[ct][j] = 0.f;

    #pragma unroll
    for (int kt = 0; kt < 4; kt++) {
        unsigned aoff = (((unsigned)mrow << 8) +
                         (((unsigned)(kt << 5) + ((lane >> 4) << 3)) << 1)) ^ swz;
        bf16x8 af = *(const bf16x8*)((const char*)xa + aoff);
        #pragma unroll
        for (int ct = 0; ct < 8; ct++) {
            const unsigned short* bp = Wt + (size_t)((ct << 4) + (lane & 15)) * 256
                                          + (kt << 5) + ((lane >> 4) << 3);
            bf16x8 bf = *(const bf16x8*)bp;
            acc[ct] = __builtin_amdgcn_mfma_f32_16x16x32_bf16(af, bf, acc[ct], 0, 0, 0);
        }
    }
    __syncthreads();

    // ---- stage phase 2: neigh -> xa (bf16, swizzled) ----
    #pragma unroll
    for (int i = 0; i < 8; i++) {
        int r  = i * 8 + (tid >> 5);
        int c4 = tid & 31;
        float4 nv = *(const float4*)(neigh + (size_t)(base + r) * H + c4 * 4);
        unsigned lo = bf_rne(nv.x) | (bf_rne(nv.y) << 16);
        unsigned hi = bf_rne(nv.z) | (bf_rne(nv.w) << 16);
        unsigned boff = ((unsigned)r << 8) + ((unsigned)c4 << 3);
        boff ^= (unsigned)((r & 7) << 4);
        *(uint2*)((char*)xa + boff) = make_uint2(lo, hi);
    }
    __syncthreads();

    // ---- MFMA phase 2: k = 128..255 (neigh part) ----
    #pragma unroll
    for (int kt = 0; kt < 4; kt++) {
        unsigned aoff = (((unsigned)mrow << 8) +
                         (((unsigned)(kt << 5) + ((lane >> 4) << 3)) << 1)) ^ swz;
        bf16x8 af = *(const bf16x8*)((const char*)xa + aoff);
        #pragma unroll
        for (int ct = 0; ct < 8; ct++) {
            const unsigned short* bp = Wt + (size_t)((ct << 4) + (lane & 15)) * 256
                                          + 128 + (kt << 5) + ((lane >> 4) << 3);
            bf16x8 bf = *(const bf16x8*)bp;
            acc[ct] = __builtin_amdgcn_mfma_f32_16x16x32_bf16(af, bf, acc[ct], 0, 0, 0);
        }
    }

    // ---- epilogue: bias + relu + residual into hold ----
    #pragma unroll
    for (int ct = 0; ct < 8; ct++) {
        int col = (ct << 4) + (lane & 15);
        float bsv = bsum[col];
        #pragma unroll
        for (int r = 0; r < 4; r++) {
            int nl = (wave << 4) + ((lane >> 4) << 2) + r;
            float v = fmaxf(acc[ct][r] + bsv, 0.f);
            hold[nl][col] += v;
        }
    }
    __syncthreads();

    // ---- writeout: h f32 + optional hb bf16 + pooling partials ----
    float csum[4] = {0.f, 0.f, 0.f, 0.f};
    float cmax[4] = {0.f, 0.f, 0.f, 0.f};
    const int c4 = tid & 31;
    #pragma unroll
    for (int i = 0; i < 8; i++) {
        int r = i * 8 + (tid >> 5);
        float4 ov = *(const float4*)&hold[r][c4 * 4];
        *(float4*)(h + (size_t)(base + r) * H + c4 * 4) = ov;
        if (hb) {
            uint2 p;
            p.x = bf_rne(ov.x) | (bf_rne(ov.y) << 16);
            p.y = bf_rne(ov.z) | (bf_rne(ov.w) << 16);
            *(uint2*)(hb + (size_t)(base + r) * 64 + c4 * 2) = p;
        }
        if (do_pool) {
            csum[0] += ov.x; cmax[0] = fmaxf(cmax[0], ov.x);
            csum[1] += ov.y; cmax[1] = fmaxf(cmax[1], ov.y);
            csum[2] += ov.z; cmax[2] = fmaxf(cmax[2], ov.z);
            csum[3] += ov.w; cmax[3] = fmaxf(cmax[3], ov.w);
        }
    }

    if (do_pool) {
        const int grp = tid >> 5;
        #pragma unroll
        for (int j = 0; j < 4; j++) {
            psum[grp][c4 * 4 + j] = csum[j];
            pmax[grp][c4 * 4 + j] = cmax[j];
        }
        __syncthreads();
        if (tid < H) {
            float s = 0.f, m = 0.f;
            #pragma unroll
            for (int gix = 0; gix < 8; gix++) {
                s += psum[gix][tid];
                m = fmaxf(m, pmax[gix][tid]);
            }
            unsafeAtomicAdd(&gout[tid], s);
            atomicMax((int*)&gout[H + tid], __float_as_int(m));
        }
    }
}

// ---------------------------------------------------------------------------
// K3 fallback (f32 VALU) — used only when workspace lacks room for Wt.
// ---------------------------------------------------------------------------
__global__ __launch_bounds__(TPB) void k_layer_dense(
    const float* __restrict__ neigh,
    const float* __restrict__ Wself, const float* __restrict__ bself,
    const float* __restrict__ Wneigh, const float* __restrict__ bneigh,
    float* __restrict__ h, unsigned* __restrict__ hb,
    float* __restrict__ gout, int do_pool)
{
    __shared__ float h_lds[NPB][H];
    __shared__ float n_lds[NPB][H];
    __shared__ float psum[8][H];
    __shared__ float pmax[8][H];
    const int tid  = threadIdx.x;
    const int base = blockIdx.x * NPB;

    for (int idx = tid; idx < NPB * H / 4; idx += TPB) {
        int r = idx >> 5, c = (idx & 31) * 4;
        *(float4*)&h_lds[r][c] = *(const float4*)(h + (size_t)(base + r) * H + c);
        *(float4*)&n_lds[r][c] = *(const float4*)(neigh + (size_t)(base + r) * H + c);
    }
    __syncthreads();

    const int c0 = (tid & 31) * 4;
    const int r0 = (tid >> 5) * 4;
    const int grp = tid >> 5;

    float acc[4][4];
    #pragma unroll
    for (int i = 0; i < 4; i++)
        #pragma unroll
        for (int j = 0; j < 4; j++) acc[i][j] = 0.f;

    for (int k = 0; k < H; k += 4) {
        float4 a[4], b[4];
        #pragma unroll
        for (int i = 0; i < 4; i++) {
            a[i] = *(const float4*)&h_lds[r0 + i][k];
            b[i] = *(const float4*)&n_lds[r0 + i][k];
        }
        #pragma unroll
        for (int kk = 0; kk < 4; kk++) {
            float4 ws = *(const float4*)(Wself  + (size_t)(k + kk) * H + c0);
            float4 wn = *(const float4*)(Wneigh + (size_t)(k + kk) * H + c0);
            const float* wsf = (const float*)&ws;
            const float* wnf = (const float*)&wn;
            #pragma unroll
            for (int i = 0; i < 4; i++) {
                float av = ((const float*)&a[i])[kk];
                float bv = ((const float*)&b[i])[kk];
                #pragma unroll
                for (int j = 0; j < 4; j++)
                    acc[i][j] += av * wsf[j] + bv * wnf[j];
            }
        }
    }

    float4 bs = *(const float4*)(bself + c0);
    float4 bn = *(const float4*)(bneigh + c0);
    const float* bsf = (const float*)&bs;
    const float* bnf = (const float*)&bn;
    float csum[4] = {0.f, 0.f, 0.f, 0.f};
    float cmax[4] = {0.f, 0.f, 0.f, 0.f};
    #pragma unroll
    for (int i = 0; i < 4; i++) {
        int node = base + r0 + i;
        float4 out;
        float* of = (float*)&out;
        #pragma unroll
        for (int j = 0; j < 4; j++) {
            float v = fmaxf(acc[i][j] + bsf[j] + bnf[j], 0.f);
            of[j] = h_lds[r0 + i][c0 + j] + v;
            csum[j] += of[j];
            cmax[j] = fmaxf(cmax[j], of[j]);
        }
        *(float4*)(h + (size_t)node * H + c0) = out;
        if (hb) {
            uint2 p;
            p.x = bf_rne(of[0]) | (bf_rne(of[1]) << 16);
            p.y = bf_rne(of[2]) | (bf_rne(of[3]) << 16);
            *(uint2*)(hb + (size_t)node * 64 + (c0 >> 1)) = p;
        }
    }

    if (do_pool) {
        #pragma unroll
        for (int j = 0; j < 4; j++) {
            psum[grp][c0 + j] = csum[j];
            pmax[grp][c0 + j] = cmax[j];
        }
        __syncthreads();
        if (tid < H) {
            float s = 0.f, m = 0.f;
            #pragma unroll
            for (int gix = 0; gix < 8; gix++) {
                s += psum[gix][tid];
                m = fmaxf(m, pmax[gix][tid]);
            }
            unsafeAtomicAdd(&gout[tid], s);
            atomicMax((int*)&gout[H + tid], __float_as_int(m));
        }
    }
}

__global__ void k_finalize(float* __restrict__ g)
{
    int t = threadIdx.x;
    if (t < 128) g[t] *= (1.0f / (float)N_NODES);
}

// ---------------------------------------------------------------------------
extern "C" void kernel_launch(void* const* d_in, const int* in_sizes, int n_in,
                              void* d_out, int out_size, void* d_ws, size_t ws_size,
                              hipStream_t stream)
{
    const int*   midx  = (const int*)  d_in[0];
    const int*   widx  = (const int*)  d_in[1];
    const int*   tidx  = (const int*)  d_in[2];
    const float* cont  = (const float*)d_in[3];
    const int*   erow  = (const int*)  d_in[4];
    const int*   ecol  = (const int*)  d_in[5];
    const float* eval  = (const float*)d_in[6];
    const float* memb  = (const float*)d_in[7];
    const float* wemb  = (const float*)d_in[8];
    const float* temb  = (const float*)d_in[9];
    const float* W1    = (const float*)d_in[10];
    const float* b1    = (const float*)d_in[11];
    const float* W2    = (const float*)d_in[12];
    const float* b2    = (const float*)d_in[13];
    const float* Wself = (const float*)d_in[14];
    const float* bself = (const float*)d_in[15];
    const float* Wneigh= (const float*)d_in[16];
    const float* bneigh= (const float*)d_in[17];

    float* g = (float*)d_out;   // [256]
    float* h = g + 256;         // [N, H] lives in d_out

    // ---- workspace layout ----
    // neigh: 102.4 MB.  bkt (phase-1 buffer, 51.2 MB) ALIASES neigh: it is
    // fully consumed by k_row_sort before the first SpMM writes neigh.
    const size_t neigh_elems = (size_t)N_NODES * H;      // 25.6 M floats
    const size_t hb_elems    = (size_t)N_NODES * H / 2;  // 12.8 M u32

    float*     neigh = (float*)d_ws;
    long long* bkt   = (long long*)d_ws;                 // alias (see above)

    // tier A layout (with hb)
    unsigned*  hb    = (unsigned*)(neigh + neigh_elems);
    long long* csrA  = (long long*)(hb + hb_elems);
    // tier B layout (no hb)
    long long* csrB  = (long long*)(neigh + neigh_elems);

    const size_t tail_ints   = (size_t)(N_NODES + 2) + NBUCK + (NBUCK + 1) + NBUCK + 16;
    const size_t WT_BYTES    = (size_t)2 * H * 256 * sizeof(unsigned short); // 128 KB
    const size_t W1T_ELEMS   = (size_t)H * 64;
    const size_t W2T_ELEMS   = (size_t)H * H;
    const size_t tierB_bytes = neigh_elems * 4 + (size_t)N_EDGES * 8 + tail_ints * 4;
    const size_t tierA_bytes = tierB_bytes + hb_elems * 4;
    const size_t tierM_bytes = tierA_bytes + 16 + 2 * H * sizeof(float) + WT_BYTES
                               + (W1T_ELEMS + W2T_ELEMS) * sizeof(unsigned short);
    const bool tierA = (ws_size >= tierA_bytes);
    const bool tierB = (ws_size >= tierB_bytes);
    const bool tierM = (ws_size >= tierM_bytes) && tierA;

    long long* csr = tierA ? csrA : csrB;
    int* row_ptr    = (int*)(csr + N_EDGES);   // N+2
    int* bhist      = row_ptr + N_NODES + 2;   // NBUCK
    int* bucket_off = bhist + NBUCK;           // NBUCK+1
    int* bucket_cur = bucket_off + NBUCK + 1;  // NBUCK

    float* bsum = (float*)(((uintptr_t)(bucket_cur + NBUCK) + 15) & ~(uintptr_t)15);
    unsigned short* Wt  = (unsigned short*)(bsum + 2 * H);
    unsigned short* W1t = Wt + (size_t)2 * H * 256;
    unsigned short* W2t = W1t + W1T_ELEMS;

    hipMemsetAsync(d_out, 0, 256 * sizeof(float), stream);

    if (tierM) {
        k_prep_w<<<3, 256, 0, stream>>>(Wself, bself, Wneigh, bneigh, W1, W2,
                                        Wt, bsum, W1t, W2t);
        k_input_mlp_mfma<<<N_NODES / DBM, TPB, 0, stream>>>(
            midx, widx, tidx, cont, memb, wemb, temb, W1t, b1, W2t, b2, h, hb);
    } else {
        k_input_mlp<<<N_NODES / NPB, TPB, 0, stream>>>(
            midx, widx, tidx, cont, memb, wemb, temb, W1, b1, W2, b2, h,
            tierA ? hb : nullptr);
    }

    if (tierB) {
        hipMemsetAsync(bhist, 0, NBUCK * sizeof(int), stream);
        k_bucket_hist<<<2048, 256, 0, stream>>>(erow, bhist);
        k_scan_buckets<<<1, 1024, 0, stream>>>(bhist, bucket_off, bucket_cur, row_ptr);
        k_bucket_sort<<<N_SORT_BLOCKS, SORT_TPB, 0, stream>>>(
            erow, ecol, eval, bucket_cur, bkt);
        k_row_sort<<<NBUCK, 512, 0, stream>>>(bucket_off, bkt, csr, row_ptr);

        for (int l = 0; l < 2; l++) {
            if (tierA) {
                k_spmm_csr_bf16<<<(N_NODES * 64 + TPB - 1) / TPB, TPB, 0, stream>>>(
                    row_ptr, (const int2*)csr, hb, neigh);
            } else {
                k_spmm_csr_f32<<<(N_NODES * 64 + TPB - 1) / TPB, TPB, 0, stream>>>(
                    row_ptr, (const int2*)csr, h, neigh);
            }
            if (tierM) {
                k_layer_dense_mfma<<<N_NODES / DBM, TPB, 0, stream>>>(
                    neigh, Wt + (size_t)l * H * 256, bsum + (size_t)l * H, h,
                    (l == 0) ? hb : nullptr, g, (l == 1) ? 1 : 0);
            } else {
                k_layer_dense<<<N_NODES / NPB, TPB, 0, stream>>>(
                    neigh, Wself + (size_t)l * H * H, bself + (size_t)l * H,
                    Wneigh + (size_t)l * H * H, bneigh + (size_t)l * H, h,
                    (tierA && l == 0) ? hb : nullptr, g, (l == 1) ? 1 : 0);
            }
        }
    } else {
        for (int l = 0; l < 2; l++) {
            hipMemsetAsync(neigh, 0, neigh_elems * sizeof(float), stream);
            unsigned int nthreads = (unsigned int)N_EDGES * 32u;
            k_spmm_atomic<<<nthreads / TPB, TPB, 0, stream>>>(erow, ecol, eval, h, neigh);
            k_layer_dense<<<N_NODES / NPB, TPB, 0, stream>>>(
                neigh, Wself + (size_t)l * H * H, bself + (size_t)l * H,
                Wneigh + (size_t)l * H * H, bneigh + (size_t)l * H, h,
                nullptr, g, (l == 1) ? 1 : 0);
        }
    }

    k_finalize<<<1, 128, 0, stream>>>(g);
}